// Round 7
// baseline (574.330 us; speedup 1.0000x reference)
//
#include <hip/hip_runtime.h>
#include <stdint.h>

// Problem constants (N,C,H,W)=(4,96,96,96), half-res 48x48
#define BN_ 4
#define CC 96
#define HF 96
#define WF 96
#define HS 48
#define WS 48
#define LL 2304      // HS*WS
#define K1 864       // CC*9  (3x3 patch feature dim)
#define J2 1536      // CC*16 (4x4 raw filter feature dim)
#define NEG10 (-1.0e10f)
#define NLT 576      // LL/4 l-tiles for fused stats

typedef __attribute__((ext_vector_type(8))) _Float16 half8v;
typedef __attribute__((ext_vector_type(4))) float float4v;

__device__ __forceinline__ int Tswap(int f) { return (f % 48) * 48 + f / 48; }

__device__ __forceinline__ unsigned short f2h(float f) {
    _Float16 h = (_Float16)f;
    return __builtin_bit_cast(unsigned short, h);
}
__device__ __forceinline__ float h2f(unsigned short u) {
    return (float)__builtin_bit_cast(_Float16, u);
}

typedef const __attribute__((address_space(1))) uint32_t* gas_ptr;
typedef __attribute__((address_space(3))) uint32_t* las_ptr;
__device__ __forceinline__ void gload16(const void* g, void* l) {
    __builtin_amdgcn_global_load_lds((gas_ptr)g, (las_ptr)l, 16, 0, 0);
}

// ---- channel-sum-of-squares of strided context: ssum[n][i][j] ----
__global__ void ssum_kernel(const float* __restrict__ ctx, float* __restrict__ ssum) {
    int idx = blockIdx.x * 256 + threadIdx.x;
    if (idx >= BN_ * HS * WS) return;
    int j = idx % WS, i = (idx / WS) % HS, n = idx / (WS * HS);
    float s = 0.f;
    for (int c = 0; c < CC; ++c) {
        float v = ctx[((size_t)(n * CC + c) * HF + 2 * i) * WF + 2 * j];
        s += v * v;
    }
    ssum[idx] = s;
}

// ---- invn[n][l] = 1/max(sqrt(sum 3x3 ssum),1e-4) ----
__global__ void invn_kernel(const float* __restrict__ ssum, float* __restrict__ invn) {
    int idx = blockIdx.x * 256 + threadIdx.x;
    if (idx >= BN_ * LL) return;
    int l = idx % LL, n = idx / LL;
    int i0 = l / WS, j0 = l % WS;
    float s = 0.f;
    for (int dy = -1; dy <= 1; ++dy)
        for (int dx = -1; dx <= 1; ++dx) {
            int i = i0 + dy, j = j0 + dx;
            if (i >= 0 && i < HS && j >= 0 && j < WS)
                s += ssum[(n * HS + i) * WS + j];
        }
    invn[idx] = 1.f / fmaxf(sqrtf(s), 1e-4f);
}

// ---- maskadd[n][l] ----
__global__ void mask_kernel(const float* __restrict__ mask, float* __restrict__ maskadd) {
    int idx = blockIdx.x * 256 + threadIdx.x;
    if (idx >= BN_ * LL) return;
    int l = idx % LL, n = idx / LL;
    int i0 = l / WS, j0 = l % WS;
    float s = 0.f;
    for (int dy = -1; dy <= 1; ++dy)
        for (int dx = -1; dx <= 1; ++dx) {
            int i = i0 + dy, j = j0 + dx;
            if (i >= 0 && i < HS && j >= 0 && j < WS)
                s += mask[(size_t)n * HF * WF + (2 * i) * WF + 2 * j];
        }
    maskadd[idx] = (s > 0.f) ? NEG10 : 0.f;
}

// ---- im2col 3x3 (pad 1) of ::2 slice + f16 hi/lo split; dst [n][l][864] k-major ----
__global__ void im2col_split(const float* __restrict__ src, const float* __restrict__ scale,
                             unsigned short* __restrict__ hi, unsigned short* __restrict__ lo) {
    int idx = blockIdx.x * 256 + threadIdx.x;
    if (idx >= BN_ * LL * K1) return;
    int k = idx % K1;
    int l = (idx / K1) % LL;
    int n = idx / (K1 * LL);
    int c = k / 9, r = k % 9;
    int i = l / WS + r / 3 - 1;
    int j = l % WS + r % 3 - 1;
    float v = 0.f;
    if (i >= 0 && i < HS && j >= 0 && j < WS)
        v = src[((size_t)(n * CC + c) * HF + 2 * i) * WF + 2 * j];
    if (scale) v *= scale[n * LL + l];
    unsigned short h = f2h(v);
    hi[idx] = h;
    lo[idx] = f2h(v - h2f(h));
}

// ---- raw filter, transposed, f16: RF[n][j][l] ----
__global__ void rf_split(const float* __restrict__ ctx, unsigned short* __restrict__ hf) {
    int idx = blockIdx.x * 256 + threadIdx.x;
    if (idx >= BN_ * J2 * LL) return;
    int l = idx % LL;
    int j = (idx / LL) % J2;
    int n = idx / (LL * J2);
    int c = j >> 4, ky = (j >> 2) & 3, kx = j & 3;
    int y = 2 * (l / WS) + ky - 1;
    int x = 2 * (l % WS) + kx - 1;
    float v = 0.f;
    if (y >= 0 && y < HF && x >= 0 && x < WF)
        v = ctx[((size_t)(n * CC + c) * HF + y) * WF + x];
    hf[idx] = f2h(v);
}

// ---- f16 MFMA GEMM, 2-phase double-buffered staging ----
// TERMS=3: Ah*Bh + Ah*Bl + Al*Bh (hi/lo f16 split).  TERMS=1: Ah*Bh.
// ODT: 0 = fp32 out, 1 = f16 out. Flat 1D grid + XCD chunk swizzle (grid%8==0).
template <int TERMS, int ODT>
__global__ __launch_bounds__(256, 4) void gemm_split(
    const unsigned short* __restrict__ Ah_, const unsigned short* __restrict__ Al_,
    const unsigned short* __restrict__ Bh_, const unsigned short* __restrict__ Bl_,
    void* __restrict__ Cout, int M_, int N_, int K_, int nbx, int nby)
{
    constexpr int NB = (TERMS == 3) ? 4 : 2;
    constexpr int BH = (TERMS == 3) ? 2 : 1;       // B_hi LDS buffer index
    constexpr int BUFS = NB * 128 * 32;            // shorts per dbuf
    __shared__ unsigned short lds[2][NB][128][32];

    int wg = blockIdx.x;
    int wgid = (wg & 7) * (gridDim.x >> 3) + (wg >> 3);
    int bx = wgid % nbx;
    int t1 = wgid / nbx;
    int by = t1 % nby;
    int bz = t1 / nby;
    const int m0 = by * 128, n0 = bx * 128;
    const int t = threadIdx.x;

    const size_t sA = (size_t)M_ * K_, sB = (size_t)N_ * K_;
    const unsigned short* Ah = Ah_ + (size_t)bz * sA;
    const unsigned short* Bh = Bh_ + (size_t)bz * sB;

    const int rloc = t >> 2;
    const int sst = t & 3;
    const int kg = sst ^ ((rloc >> 1) & 3);
    const size_t offA0 = (size_t)(m0 + rloc) * K_ + kg * 8;
    const size_t offA1 = (size_t)(m0 + 64 + rloc) * K_ + kg * 8;
    const size_t offB0 = (size_t)(n0 + rloc) * K_ + kg * 8;
    const size_t offB1 = (size_t)(n0 + 64 + rloc) * K_ + kg * 8;
    const unsigned short* gpA0 = Ah + offA0;
    const unsigned short* gpA1 = Ah + offA1;
    const unsigned short* gpB0 = Bh + offB0;
    const unsigned short* gpB1 = Bh + offB1;
    const unsigned short* gpAl0 = nullptr;
    const unsigned short* gpAl1 = nullptr;
    const unsigned short* gpBl0 = nullptr;
    const unsigned short* gpBl1 = nullptr;
    if constexpr (TERMS == 3) {
        const unsigned short* Al = Al_ + (size_t)bz * sA;
        const unsigned short* Bl = Bl_ + (size_t)bz * sB;
        gpAl0 = Al + offA0;
        gpAl1 = Al + offA1;
        gpBl0 = Bl + offB0;
        gpBl1 = Bl + offB1;
    }
    // per-thread LDS short-offsets (within one dbuf)
    const int oA0 = (0 * 128 + rloc) * 32 + sst * 8;
    const int oA1 = (0 * 128 + 64 + rloc) * 32 + sst * 8;
    const int oAl0 = (1 * 128 + rloc) * 32 + sst * 8;
    const int oAl1 = (1 * 128 + 64 + rloc) * 32 + sst * 8;
    const int oB0 = (BH * 128 + rloc) * 32 + sst * 8;
    const int oB1 = (BH * 128 + 64 + rloc) * 32 + sst * 8;
    const int oBl0 = (3 * 128 + rloc) * 32 + sst * 8;
    const int oBl1 = (3 * 128 + 64 + rloc) * 32 + sst * 8;
    unsigned short* L = &lds[0][0][0][0];

#define STAGEB(buf) do { \
        unsigned short* Lb = L + (buf) * BUFS; \
        gload16(gpA0, Lb + oA0); gload16(gpA1, Lb + oA1); \
        gload16(gpB0, Lb + oB0); gload16(gpB1, Lb + oB1); \
        if constexpr (TERMS == 3) { \
            gload16(gpAl0, Lb + oAl0); gload16(gpAl1, Lb + oAl1); \
            gload16(gpBl0, Lb + oBl0); gload16(gpBl1, Lb + oBl1); \
        } \
        gpA0 += 32; gpA1 += 32; gpB0 += 32; gpB1 += 32; \
        if constexpr (TERMS == 3) { gpAl0 += 32; gpAl1 += 32; gpBl0 += 32; gpBl1 += 32; } \
    } while (0)

    const int lane = t & 63;
    const int w = t >> 6, wr = w >> 1, wc = w & 1;
    const int lr = lane & 15, lg = lane >> 4;

    float4v acc[4][4] = {};
    const int nt = K_ / 32;

    STAGEB(0);                 // prologue: tile 0 -> buf 0
    __syncthreads();           // drains vmcnt(0) before first compute
    int cur = 0;
    for (int kt = 0; kt < nt; ++kt) {
        if (kt + 1 < nt) STAGEB(cur ^ 1);   // issue next tile BEFORE compute (2-phase)

        half8v bh[4], bl[4];
#pragma unroll
        for (int j = 0; j < 4; ++j) {
            int row = wc * 64 + j * 16 + lr;
            int s = (lg ^ ((row >> 1) & 3)) * 8;
            bh[j] = *(const half8v*)&lds[cur][BH][row][s];
            if constexpr (TERMS == 3) bl[j] = *(const half8v*)&lds[cur][3][row][s];
        }
#pragma unroll
        for (int i = 0; i < 4; ++i) {
            int row = wr * 64 + i * 16 + lr;
            int s = (lg ^ ((row >> 1) & 3)) * 8;
            half8v ah = *(const half8v*)&lds[cur][0][row][s];
#pragma unroll
            for (int j = 0; j < 4; ++j) {
                acc[i][j] = __builtin_amdgcn_mfma_f32_16x16x32_f16(ah, bh[j], acc[i][j], 0, 0, 0);
                if constexpr (TERMS == 3) {
                    half8v al = *(const half8v*)&lds[cur][1][row][s];
                    acc[i][j] = __builtin_amdgcn_mfma_f32_16x16x32_f16(ah, bl[j], acc[i][j], 0, 0, 0);
                    acc[i][j] = __builtin_amdgcn_mfma_f32_16x16x32_f16(al, bh[j], acc[i][j], 0, 0, 0);
                }
            }
        }
        __syncthreads();       // one barrier per K-step (drains stage vmcnt + lgkm)
        cur ^= 1;
    }
#undef STAGEB

    if constexpr (ODT == 0) {
        float* Cb = (float*)Cout + (size_t)bz * M_ * N_;
#pragma unroll
        for (int i = 0; i < 4; ++i) {
            int mb = m0 + wr * 64 + i * 16 + lg * 4;
#pragma unroll
            for (int j = 0; j < 4; ++j) {
                int nn = n0 + wc * 64 + j * 16 + lr;
#pragma unroll
                for (int r = 0; r < 4; ++r)
                    Cb[(size_t)(mb + r) * N_ + nn] = acc[i][j][r];
            }
        }
    } else {
        unsigned short* Gb = (unsigned short*)Cout + (size_t)bz * M_ * N_;
#pragma unroll
        for (int i = 0; i < 4; ++i) {
            int mb = m0 + wr * 64 + i * 16 + lg * 4;
#pragma unroll
            for (int j = 0; j < 4; ++j) {
                int nn = n0 + wc * 64 + j * 16 + lr;
#pragma unroll
                for (int r = 0; r < 4; ++r)
                    Gb[(size_t)(mb + r) * N_ + nn] = f2h(acc[i][j][r]);
            }
        }
    }
}

// ---- fused double conv_eye + mask + x10 AND per-tile softmax partials ----
// block 256 = 64p x 4l; grid (LL/64, LL/4, BN_). Writes F[l][p], pm/ps[n][lt][p].
__global__ __launch_bounds__(256) void fuse_stat(const float* __restrict__ S,
                                                 const float* __restrict__ maskadd,
                                                 float* __restrict__ F,
                                                 float* __restrict__ pm,
                                                 float* __restrict__ ps) {
    __shared__ float tile[4][65];
    int pb = blockIdx.x, lb = blockIdx.y, n = blockIdx.z;
    int tx = threadIdx.x & 63, ty = threadIdx.x >> 6;
    int p = pb * 64 + tx;
    int l = lb * 4 + ty;
    const float* Sb = S + (size_t)n * LL * LL;
    int Tl = Tswap(l), Tp = Tswap(p);
    float acc = 0.f;
#pragma unroll
    for (int d2 = -1; d2 <= 1; ++d2) {
        int fl = Tl + d2, fp = Tp + d2;
        if (fl < 0 || fl >= LL || fp < 0 || fp >= LL) continue;
        int l2 = Tswap(fl), p2 = Tswap(fp);
#pragma unroll
        for (int d1 = -1; d1 <= 1; ++d1) {
            int l3 = l2 + d1, p3 = p2 + d1;
            if (l3 < 0 || l3 >= LL || p3 < 0 || p3 >= LL) continue;
            acc += Sb[(size_t)l3 * LL + p3];
        }
    }
    float Fv = acc * 10.f + maskadd[n * LL + l];
    F[((size_t)n * LL + l) * LL + p] = Fv;
    tile[ty][tx] = Fv;
    __syncthreads();
    if (ty == 0) {
        float m = tile[0][tx];
#pragma unroll
        for (int r = 1; r < 4; ++r) m = fmaxf(m, tile[r][tx]);
        float s = 0.f;
#pragma unroll
        for (int r = 0; r < 4; ++r) s += __expf(tile[r][tx] - m);
        pm[((size_t)n * NLT + lb) * LL + p] = m;
        ps[((size_t)n * NLT + lb) * LL + p] = s;
    }
}

// ---- merge 576 partials -> mstat[p], sinv[p]; block 256 = 64p x 4 strides ----
__global__ __launch_bounds__(256) void mergestat_kernel(const float* __restrict__ pm,
                                                        const float* __restrict__ ps,
                                                        float* __restrict__ mstat,
                                                        float* __restrict__ sinv) {
    __shared__ float ms[4][65], ss[4][65];
    int pb = blockIdx.x, n = blockIdx.y;
    int tx = threadIdx.x & 63, q = threadIdx.x >> 6;
    int p = pb * 64 + tx;
    float m = -3e38f, s = 0.f;
    for (int tl = q; tl < NLT; tl += 4) {
        float m2 = pm[((size_t)n * NLT + tl) * LL + p];
        float s2 = ps[((size_t)n * NLT + tl) * LL + p];
        float mm = fmaxf(m, m2);
        s = s * __expf(m - mm) + s2 * __expf(m2 - mm);
        m = mm;
    }
    ms[q][tx] = m; ss[q][tx] = s;
    __syncthreads();
    if (q == 0) {
#pragma unroll
        for (int r = 1; r < 4; ++r) {
            float m2 = ms[r][tx], s2 = ss[r][tx];
            float mm = fmaxf(m, m2);
            s = s * __expf(m - mm) + s2 * __expf(m2 - mm);
            m = mm;
        }
        mstat[n * LL + p] = m;
        sinv[n * LL + p] = 1.f / s;
    }
}

// ---- finish: att = exp(F-m)*sinv in place; emit transposed f16 attT[p][l] ----
__global__ __launch_bounds__(256) void finish_kernel(float* __restrict__ F,
                                                     const float* __restrict__ mstat,
                                                     const float* __restrict__ sinv,
                                                     unsigned short* __restrict__ Th) {
    __shared__ float tile[32][33];
    int n = blockIdx.z;
    int l0 = blockIdx.y * 32, p0 = blockIdx.x * 32;
    float* Fb = F + (size_t)n * LL * LL;
    int tx = threadIdx.x & 31, ty = threadIdx.x >> 5;
    float m = mstat[n * LL + p0 + tx];
    float si = sinv[n * LL + p0 + tx];
#pragma unroll
    for (int q = 0; q < 4; ++q) {
        int l = l0 + ty + q * 8;
        size_t o = (size_t)l * LL + p0 + tx;
        float e = __expf(Fb[o] - m) * si;
        Fb[o] = e;                 // in-place: F -> att (same element)
        tile[ty + q * 8][tx] = e;  // tile[li][pi]
    }
    __syncthreads();
#pragma unroll
    for (int q = 0; q < 4; ++q) {
        int p = p0 + ty + q * 8;
        float v = tile[tx][ty + q * 8];   // (p, l0+tx)
        Th[((size_t)n * LL + p) * LL + l0 + tx] = f2h(v);
    }
}

// ---- col2im gather from f16 G[p][j] + overlap division ----
__global__ void col2im_kernel(const unsigned short* __restrict__ G, float* __restrict__ out) {
    int idx = blockIdx.x * 256 + threadIdx.x;
    if (idx >= BN_ * CC * HF * WF) return;
    int x = idx % WF;
    int y = (idx / WF) % HF;
    int c = (idx / (WF * HF)) % CC;
    int n = idx / (WF * HF * CC);
    const unsigned short* Gb = G + (size_t)n * LL * J2;
    float acc = 0.f;
#pragma unroll
    for (int ky = 0; ky < 4; ++ky) {
        int ynum = y + 1 - ky;
        if (ynum & 1) continue;
        int iy = ynum >> 1;
        if (iy < 0 || iy >= HS) continue;
#pragma unroll
        for (int kx = 0; kx < 4; ++kx) {
            int xnum = x + 1 - kx;
            if (xnum & 1) continue;
            int ix = xnum >> 1;
            if (ix < 0 || ix >= WS) continue;
            acc += h2f(Gb[(size_t)(iy * WS + ix) * J2 + c * 16 + ky * 4 + kx]);
        }
    }
    float cy = (y == 0 || y == HF - 1) ? 1.f : 2.f;
    float cx = (x == 0 || x == WF - 1) ? 1.f : 2.f;
    out[idx] = acc / (cy * cx);
}

extern "C" void kernel_launch(void* const* d_in, const int* in_sizes, int n_in,
                              void* d_out, int out_size, void* d_ws, size_t ws_size,
                              hipStream_t stream) {
    const float* x       = (const float*)d_in[0];
    const float* context = (const float*)d_in[1];
    const float* mask    = (const float*)d_in[2];

    float* out = (float*)d_out;                                  // [4][96][96][96]
    float* att_region = out + (size_t)BN_ * CC * HF * WF;        // [4][2304][2304] fp32

    // workspace layout (bytes); proven ws_size >= 148,672,512.
    //  phase A (through GEMM1): cols/xp f16-splits @[0,63.7M) ; S @[63.7M,148.6M) ;
    //           ssum/invn @63.7M (dead before S written) ; maskadd @148,635,648
    //  fuse_stat: reads S -> writes F (d_out) + pm @[0,21.2M) + ps @[21.2M,42.5M)
    //  mergestat: pm/ps -> mstat @42,467,328, sinv @42,504,192   (S dead now)
    //  finish: F -> att in place + Th @[0,42.5M) (clobbers dead pm/ps)
    //  phase C: RF f16 @84,934,656 ; G f16 @113,246,208 (dead S region)
    char* wsb = (char*)d_ws;
    const size_t EK1 = (size_t)BN_ * LL * K1;      // 7,962,624
    const size_t ERF = (size_t)BN_ * J2 * LL;      // 14,155,776
    unsigned short* cols_hi = (unsigned short*)wsb;
    unsigned short* cols_lo = cols_hi + EK1;
    unsigned short* xp_hi   = cols_lo + EK1;
    unsigned short* xp_lo   = xp_hi + EK1;
    float* S = (float*)(wsb + 63700992);
    float* pm = (float*)wsb;                                      // [4][576][2304]
    float* ps = pm + (size_t)BN_ * NLT * LL;
    float* mstat = (float*)(wsb + 42467328);                      // [4][2304]
    float* sinv  = mstat + BN_ * LL;
    unsigned short* Th = (unsigned short*)wsb;                    // after mergestat
    unsigned short* RF = (unsigned short*)(wsb + 84934656);       // after fuse_stat (S dead)
    unsigned short* G  = (unsigned short*)(wsb + 113246208);
    float* ssum    = (float*)(wsb + 63700992);                    // dead before S written
    float* invn    = ssum + BN_ * HS * WS;
    float* maskadd = (float*)(wsb + 148635648);

    ssum_kernel<<<(BN_ * HS * WS + 255) / 256, 256, 0, stream>>>(context, ssum);
    invn_kernel<<<(BN_ * LL + 255) / 256, 256, 0, stream>>>(ssum, invn);
    mask_kernel<<<(BN_ * LL + 255) / 256, 256, 0, stream>>>(mask, maskadd);

    im2col_split<<<(int)(EK1 / 256), 256, 0, stream>>>(x, nullptr, xp_hi, xp_lo);
    im2col_split<<<(int)(EK1 / 256), 256, 0, stream>>>(context, invn, cols_hi, cols_lo);

    // GEMM1 (3-term f16 split, 2-phase): S[l][p] = cols . xp^T (fp32)
    gemm_split<3, 0><<<(LL / 128) * (LL / 128) * BN_, 256, 0, stream>>>(
        cols_hi, cols_lo, xp_hi, xp_lo, S, LL, LL, K1, LL / 128, LL / 128);

    // fuse (both conv_eye passes) + mask + x10 -> F (d_out) with fused softmax partials
    fuse_stat<<<dim3(LL / 64, LL / 4, BN_), 256, 0, stream>>>(S, maskadd, att_region, pm, ps);
    mergestat_kernel<<<dim3(LL / 64, BN_), 256, 0, stream>>>(pm, ps, mstat, sinv);
    finish_kernel<<<dim3(LL / 32, LL / 32, BN_), 256, 0, stream>>>(att_region, mstat, sinv, Th);

    // raw filters f16 (S dead now)
    rf_split<<<(int)(ERF / 256), 256, 0, stream>>>(context, RF);

    // GEMM2 (1-term f16, 2-phase): G[p][j] = att^T . RF^T  (f16 out)
    gemm_split<1, 1><<<(J2 / 128) * (LL / 128) * BN_, 256, 0, stream>>>(
        Th, nullptr, RF, nullptr, G, LL, J2, LL, J2 / 128, LL / 128);

    // col2im gather + overlap normalization -> out
    col2im_kernel<<<(BN_ * CC * HF * WF + 255) / 256, 256, 0, stream>>>(G, out);
}

// Round 8
// 518.211 us; speedup vs baseline: 1.1083x; 1.1083x over previous
//
#include <hip/hip_runtime.h>
#include <stdint.h>

// Problem constants (N,C,H,W)=(4,96,96,96), half-res 48x48
#define BN_ 4
#define CC 96
#define HF 96
#define WF 96
#define HS 48
#define WS 48
#define LL 2304      // HS*WS
#define K1 864       // CC*9  (3x3 patch feature dim)
#define J2 1536      // CC*16 (4x4 raw filter feature dim)
#define NEG10 (-1.0e10f)

typedef __attribute__((ext_vector_type(8))) _Float16 half8v;
typedef __attribute__((ext_vector_type(4))) float float4v;

__device__ __forceinline__ int Tswap(int f) { return (f % 48) * 48 + f / 48; }

__device__ __forceinline__ unsigned short f2h(float f) {
    _Float16 h = (_Float16)f;
    return __builtin_bit_cast(unsigned short, h);
}
__device__ __forceinline__ float h2f(unsigned short u) {
    return (float)__builtin_bit_cast(_Float16, u);
}

typedef const __attribute__((address_space(1))) uint32_t* gas_ptr;
typedef __attribute__((address_space(3))) uint32_t* las_ptr;
__device__ __forceinline__ void gload16(const void* g, void* l) {
    __builtin_amdgcn_global_load_lds((gas_ptr)g, (las_ptr)l, 16, 0, 0);
}

// ---- channel-sum-of-squares of strided context: ssum[n][i][j] ----
__global__ void ssum_kernel(const float* __restrict__ ctx, float* __restrict__ ssum) {
    int idx = blockIdx.x * 256 + threadIdx.x;
    if (idx >= BN_ * HS * WS) return;
    int j = idx % WS, i = (idx / WS) % HS, n = idx / (WS * HS);
    float s = 0.f;
    for (int c = 0; c < CC; ++c) {
        float v = ctx[((size_t)(n * CC + c) * HF + 2 * i) * WF + 2 * j];
        s += v * v;
    }
    ssum[idx] = s;
}

// ---- invn[n][l] = 1/max(sqrt(sum 3x3 ssum),1e-4) ----
__global__ void invn_kernel(const float* __restrict__ ssum, float* __restrict__ invn) {
    int idx = blockIdx.x * 256 + threadIdx.x;
    if (idx >= BN_ * LL) return;
    int l = idx % LL, n = idx / LL;
    int i0 = l / WS, j0 = l % WS;
    float s = 0.f;
    for (int dy = -1; dy <= 1; ++dy)
        for (int dx = -1; dx <= 1; ++dx) {
            int i = i0 + dy, j = j0 + dx;
            if (i >= 0 && i < HS && j >= 0 && j < WS)
                s += ssum[(n * HS + i) * WS + j];
        }
    invn[idx] = 1.f / fmaxf(sqrtf(s), 1e-4f);
}

// ---- maskadd[n][l] ----
__global__ void mask_kernel(const float* __restrict__ mask, float* __restrict__ maskadd) {
    int idx = blockIdx.x * 256 + threadIdx.x;
    if (idx >= BN_ * LL) return;
    int l = idx % LL, n = idx / LL;
    int i0 = l / WS, j0 = l % WS;
    float s = 0.f;
    for (int dy = -1; dy <= 1; ++dy)
        for (int dx = -1; dx <= 1; ++dx) {
            int i = i0 + dy, j = j0 + dx;
            if (i >= 0 && i < HS && j >= 0 && j < WS)
                s += mask[(size_t)n * HF * WF + (2 * i) * WF + 2 * j];
        }
    maskadd[idx] = (s > 0.f) ? NEG10 : 0.f;
}

// ---- im2col 3x3 (pad 1) of ::2 slice + f16 hi/lo split; dst [n][l][864] k-major ----
__global__ void im2col_split(const float* __restrict__ src, const float* __restrict__ scale,
                             unsigned short* __restrict__ hi, unsigned short* __restrict__ lo) {
    int idx = blockIdx.x * 256 + threadIdx.x;
    if (idx >= BN_ * LL * K1) return;
    int k = idx % K1;
    int l = (idx / K1) % LL;
    int n = idx / (K1 * LL);
    int c = k / 9, r = k % 9;
    int i = l / WS + r / 3 - 1;
    int j = l % WS + r % 3 - 1;
    float v = 0.f;
    if (i >= 0 && i < HS && j >= 0 && j < WS)
        v = src[((size_t)(n * CC + c) * HF + 2 * i) * WF + 2 * j];
    if (scale) v *= scale[n * LL + l];
    unsigned short h = f2h(v);
    hi[idx] = h;
    lo[idx] = f2h(v - h2f(h));
}

// ---- raw filter, transposed, f16: RF[n][j][l] ----
__global__ void rf_split(const float* __restrict__ ctx, unsigned short* __restrict__ hf) {
    int idx = blockIdx.x * 256 + threadIdx.x;
    if (idx >= BN_ * J2 * LL) return;
    int l = idx % LL;
    int j = (idx / LL) % J2;
    int n = idx / (LL * J2);
    int c = j >> 4, ky = (j >> 2) & 3, kx = j & 3;
    int y = 2 * (l / WS) + ky - 1;
    int x = 2 * (l % WS) + kx - 1;
    float v = 0.f;
    if (y >= 0 && y < HF && x >= 0 && x < WF)
        v = ctx[((size_t)(n * CC + c) * HF + y) * WF + x];
    hf[idx] = f2h(v);
}

// ---- f16 MFMA GEMM: C[m][n] = sum_k A[m][k]*B[n][k] ----
// TERMS=3: Ah*Bh + Ah*Bl + Al*Bh (hi/lo f16 split), single-buffer (32 KB LDS).
// TERMS=1: Ah*Bh, 2-phase double-buffered (32 KB LDS total).
// ODT: 0 = fp32 out, 1 = f16 out. Flat 1D grid + XCD chunk swizzle (grid%8==0).
template <int TERMS, int ODT>
__global__ __launch_bounds__(256, 4) void gemm_split(
    const unsigned short* __restrict__ Ah_, const unsigned short* __restrict__ Al_,
    const unsigned short* __restrict__ Bh_, const unsigned short* __restrict__ Bl_,
    void* __restrict__ Cout, int M_, int N_, int K_, int nbx, int nby)
{
    constexpr int NB = (TERMS == 3) ? 4 : 2;
    constexpr int BH = (TERMS == 3) ? 2 : 1;       // B_hi LDS buffer index
    constexpr int NBUF = (TERMS == 1) ? 2 : 1;     // dbuf only for the light GEMM
    constexpr int BUFS = NB * 128 * 32;            // shorts per dbuf
    __shared__ unsigned short lds[NBUF][NB][128][32];

    int wg = blockIdx.x;
    int wgid = (wg & 7) * (gridDim.x >> 3) + (wg >> 3);
    int bx = wgid % nbx;
    int t1 = wgid / nbx;
    int by = t1 % nby;
    int bz = t1 / nby;
    const int m0 = by * 128, n0 = bx * 128;
    const int t = threadIdx.x;

    const size_t sA = (size_t)M_ * K_, sB = (size_t)N_ * K_;
    const unsigned short* Ah = Ah_ + (size_t)bz * sA;
    const unsigned short* Bh = Bh_ + (size_t)bz * sB;

    const int rloc = t >> 2;
    const int sst = t & 3;
    const int kg = sst ^ ((rloc >> 1) & 3);
    const size_t offA0 = (size_t)(m0 + rloc) * K_ + kg * 8;
    const size_t offA1 = (size_t)(m0 + 64 + rloc) * K_ + kg * 8;
    const size_t offB0 = (size_t)(n0 + rloc) * K_ + kg * 8;
    const size_t offB1 = (size_t)(n0 + 64 + rloc) * K_ + kg * 8;
    const unsigned short* gpA0 = Ah + offA0;
    const unsigned short* gpA1 = Ah + offA1;
    const unsigned short* gpB0 = Bh + offB0;
    const unsigned short* gpB1 = Bh + offB1;
    const unsigned short* gpAl0 = nullptr;
    const unsigned short* gpAl1 = nullptr;
    const unsigned short* gpBl0 = nullptr;
    const unsigned short* gpBl1 = nullptr;
    if constexpr (TERMS == 3) {
        const unsigned short* Al = Al_ + (size_t)bz * sA;
        const unsigned short* Bl = Bl_ + (size_t)bz * sB;
        gpAl0 = Al + offA0;
        gpAl1 = Al + offA1;
        gpBl0 = Bl + offB0;
        gpBl1 = Bl + offB1;
    }
    // per-thread LDS short-offsets (within one buffer set)
    const int oA0 = (0 * 128 + rloc) * 32 + sst * 8;
    const int oA1 = (0 * 128 + 64 + rloc) * 32 + sst * 8;
    const int oAl0 = (1 * 128 + rloc) * 32 + sst * 8;
    const int oAl1 = (1 * 128 + 64 + rloc) * 32 + sst * 8;
    const int oB0 = (BH * 128 + rloc) * 32 + sst * 8;
    const int oB1 = (BH * 128 + 64 + rloc) * 32 + sst * 8;
    const int oBl0 = (3 * 128 + rloc) * 32 + sst * 8;
    const int oBl1 = (3 * 128 + 64 + rloc) * 32 + sst * 8;
    unsigned short* L = &lds[0][0][0][0];

#define STAGEB(buf) do { \
        unsigned short* Lb = L + (buf) * BUFS; \
        gload16(gpA0, Lb + oA0); gload16(gpA1, Lb + oA1); \
        gload16(gpB0, Lb + oB0); gload16(gpB1, Lb + oB1); \
        if constexpr (TERMS == 3) { \
            gload16(gpAl0, Lb + oAl0); gload16(gpAl1, Lb + oAl1); \
            gload16(gpBl0, Lb + oBl0); gload16(gpBl1, Lb + oBl1); \
        } \
        gpA0 += 32; gpA1 += 32; gpB0 += 32; gpB1 += 32; \
        if constexpr (TERMS == 3) { gpAl0 += 32; gpAl1 += 32; gpBl0 += 32; gpBl1 += 32; } \
    } while (0)

    const int lane = t & 63;
    const int w = t >> 6, wr = w >> 1, wc = w & 1;
    const int lr = lane & 15, lg = lane >> 4;

    float4v acc[4][4] = {};
    const int nt = K_ / 32;

#define COMPUTE(buf) do { \
        half8v bh[4], bl[4]; \
        _Pragma("unroll") \
        for (int j = 0; j < 4; ++j) { \
            int row = wc * 64 + j * 16 + lr; \
            int s = (lg ^ ((row >> 1) & 3)) * 8; \
            bh[j] = *(const half8v*)&lds[buf][BH][row][s]; \
            if constexpr (TERMS == 3) bl[j] = *(const half8v*)&lds[buf][3][row][s]; \
        } \
        _Pragma("unroll") \
        for (int i = 0; i < 4; ++i) { \
            int row = wr * 64 + i * 16 + lr; \
            int s = (lg ^ ((row >> 1) & 3)) * 8; \
            half8v ah = *(const half8v*)&lds[buf][0][row][s]; \
            _Pragma("unroll") \
            for (int j = 0; j < 4; ++j) { \
                acc[i][j] = __builtin_amdgcn_mfma_f32_16x16x32_f16(ah, bh[j], acc[i][j], 0, 0, 0); \
                if constexpr (TERMS == 3) { \
                    half8v al = *(const half8v*)&lds[buf][1][row][s]; \
                    acc[i][j] = __builtin_amdgcn_mfma_f32_16x16x32_f16(ah, bl[j], acc[i][j], 0, 0, 0); \
                    acc[i][j] = __builtin_amdgcn_mfma_f32_16x16x32_f16(al, bh[j], acc[i][j], 0, 0, 0); \
                } \
            } \
        } \
    } while (0)

    if constexpr (NBUF == 1) {
        // single-buffer 1-phase (proven round-6 structure)
        for (int kt = 0; kt < nt; ++kt) {
            __syncthreads();
            STAGEB(0);
            __syncthreads();
            COMPUTE(0);
        }
    } else {
        // 2-phase double-buffered (proven round-7 structure, 32 KB total)
        STAGEB(0);
        __syncthreads();
        int cur = 0;
        for (int kt = 0; kt < nt; ++kt) {
            if (kt + 1 < nt) STAGEB(cur ^ 1);
            COMPUTE(cur);
            __syncthreads();
            cur ^= 1;
        }
    }
#undef STAGEB
#undef COMPUTE

    if constexpr (ODT == 0) {
        float* Cb = (float*)Cout + (size_t)bz * M_ * N_;
#pragma unroll
        for (int i = 0; i < 4; ++i) {
            int mb = m0 + wr * 64 + i * 16 + lg * 4;
#pragma unroll
            for (int j = 0; j < 4; ++j) {
                int nn = n0 + wc * 64 + j * 16 + lr;
#pragma unroll
                for (int r = 0; r < 4; ++r)
                    Cb[(size_t)(mb + r) * N_ + nn] = acc[i][j][r];
            }
        }
    } else {
        unsigned short* Gb = (unsigned short*)Cout + (size_t)bz * M_ * N_;
#pragma unroll
        for (int i = 0; i < 4; ++i) {
            int mb = m0 + wr * 64 + i * 16 + lg * 4;
#pragma unroll
            for (int j = 0; j < 4; ++j) {
                int nn = n0 + wc * 64 + j * 16 + lr;
#pragma unroll
                for (int r = 0; r < 4; ++r)
                    Gb[(size_t)(mb + r) * N_ + nn] = f2h(acc[i][j][r]);
            }
        }
    }
}

// ---- fused double conv_eye + mask + x10, one thread per element: F[l][p] ----
__global__ void fuse_kernel(const float* __restrict__ S, const float* __restrict__ maskadd,
                            float* __restrict__ Sf) {
    int wg = blockIdx.x;
    int wgid = (wg & 7) * (gridDim.x >> 3) + (wg >> 3);
    int idx = wgid * 256 + threadIdx.x;
    int p = idx % LL;
    int l = (idx / LL) % LL;
    int n = idx / (LL * LL);
    const float* Sb = S + (size_t)n * LL * LL;
    int Tl = Tswap(l), Tp = Tswap(p);
    float acc = 0.f;
#pragma unroll
    for (int d2 = -1; d2 <= 1; ++d2) {
        int fl = Tl + d2, fp = Tp + d2;
        if (fl < 0 || fl >= LL || fp < 0 || fp >= LL) continue;
        int l2 = Tswap(fl), p2 = Tswap(fp);
#pragma unroll
        for (int d1 = -1; d1 <= 1; ++d1) {
            int l3 = l2 + d1, p3 = p2 + d1;
            if (l3 < 0 || l3 >= LL || p3 < 0 || p3 >= LL) continue;
            acc += Sb[(size_t)l3 * LL + p3];
        }
    }
    Sf[idx] = acc * 10.f + maskadd[n * LL + l];
}

// ---- column-wise online softmax stats over F[l][p]: partial (m,s) per l-split ----
// grid (36 p-blocks, 8 l-splits, 4 n), block 256 = 64 p x 4 l-rows
__global__ __launch_bounds__(256) void colstat_kernel(const float* __restrict__ F,
                                                      float* __restrict__ pm,
                                                      float* __restrict__ ps) {
    __shared__ float ms[4][64], ss[4][64];
    int pb = blockIdx.x, lsp = blockIdx.y, n = blockIdx.z;
    int tx = threadIdx.x & 63;
    int ty = threadIdx.x >> 6;
    int p = pb * 64 + tx;
    const float* Fb = F + (size_t)n * LL * LL;
    float m = -3e38f, s = 0.f;
    int l_end = (lsp + 1) * 288;
    for (int l = lsp * 288 + ty; l < l_end; l += 4) {
        float v = Fb[(size_t)l * LL + p];
        float mm = fmaxf(m, v);
        s = s * __expf(m - mm) + __expf(v - mm);
        m = mm;
    }
    ms[ty][tx] = m; ss[ty][tx] = s;
    __syncthreads();
    if (ty == 0) {
#pragma unroll
        for (int q = 1; q < 4; ++q) {
            float m2 = ms[q][tx], s2 = ss[q][tx];
            float mm = fmaxf(m, m2);
            s = s * __expf(m - mm) + s2 * __expf(m2 - mm);
            m = mm;
        }
        pm[((size_t)n * 8 + lsp) * LL + p] = m;
        ps[((size_t)n * 8 + lsp) * LL + p] = s;
    }
}

// ---- merge 8 partials -> mstat[p], sinv[p] ----
__global__ void mergestat_kernel(const float* __restrict__ pm, const float* __restrict__ ps,
                                 float* __restrict__ mstat, float* __restrict__ sinv) {
    int idx = blockIdx.x * 256 + threadIdx.x;
    if (idx >= BN_ * LL) return;
    int n = idx / LL, p = idx % LL;
    float m = -3e38f, s = 0.f;
#pragma unroll
    for (int q = 0; q < 8; ++q) {
        float m2 = pm[((size_t)n * 8 + q) * LL + p];
        float s2 = ps[((size_t)n * 8 + q) * LL + p];
        float mm = fmaxf(m, m2);
        s = s * __expf(m - mm) + s2 * __expf(m2 - mm);
        m = mm;
    }
    mstat[idx] = m;
    sinv[idx] = 1.f / s;
}

// ---- finish 64x64: att = exp(F-m)*sinv in place (float4); emit f16 attT (uint4) ----
// block 256 = 16 p-quads x 16 rows; grid (LL/64, LL/64, BN_)
__global__ __launch_bounds__(256) void finish_kernel(float* __restrict__ F,
                                                     const float* __restrict__ mstat,
                                                     const float* __restrict__ sinv,
                                                     unsigned short* __restrict__ Th) {
    __shared__ float tile[64][65];
    int n = blockIdx.z;
    int l0 = blockIdx.y * 64, p0 = blockIdx.x * 64;
    float* Fb = F + (size_t)n * LL * LL;
    int tx = threadIdx.x & 15, ty = threadIdx.x >> 4;
    float4v m4 = *(const float4v*)&mstat[n * LL + p0 + tx * 4];
    float4v s4 = *(const float4v*)&sinv[n * LL + p0 + tx * 4];
#pragma unroll
    for (int q = 0; q < 4; ++q) {
        int lr = q * 16 + ty;
        float4v v = *(const float4v*)&Fb[(size_t)(l0 + lr) * LL + p0 + tx * 4];
        float4v e;
#pragma unroll
        for (int i = 0; i < 4; ++i) e[i] = __expf(v[i] - m4[i]) * s4[i];
        *(float4v*)&Fb[(size_t)(l0 + lr) * LL + p0 + tx * 4] = e;
#pragma unroll
        for (int i = 0; i < 4; ++i) tile[lr][tx * 4 + i] = e[i];
    }
    __syncthreads();
    // write Th[p][l]: thread covers p-row pr (64 rows), l-chunk lq*16 (16 f16 = 32 B)
    int pr = threadIdx.x >> 2, lq = threadIdx.x & 3;
    uint32_t u[8];
#pragma unroll
    for (int i = 0; i < 8; ++i) {
        unsigned short h0 = f2h(tile[lq * 16 + 2 * i][pr]);
        unsigned short h1 = f2h(tile[lq * 16 + 2 * i + 1][pr]);
        u[i] = (uint32_t)h0 | ((uint32_t)h1 << 16);
    }
    unsigned short* dst = &Th[((size_t)n * LL + p0 + pr) * LL + l0 + lq * 16];
    ((uint32_t*)dst)[0] = u[0]; ((uint32_t*)dst)[1] = u[1];
    ((uint32_t*)dst)[2] = u[2]; ((uint32_t*)dst)[3] = u[3];
    ((uint32_t*)dst)[4] = u[4]; ((uint32_t*)dst)[5] = u[5];
    ((uint32_t*)dst)[6] = u[6]; ((uint32_t*)dst)[7] = u[7];
}

// ---- col2im gather from f16 G[p][j] + overlap division ----
__global__ void col2im_kernel(const unsigned short* __restrict__ G, float* __restrict__ out) {
    int idx = blockIdx.x * 256 + threadIdx.x;
    if (idx >= BN_ * CC * HF * WF) return;
    int x = idx % WF;
    int y = (idx / WF) % HF;
    int c = (idx / (WF * HF)) % CC;
    int n = idx / (WF * HF * CC);
    const unsigned short* Gb = G + (size_t)n * LL * J2;
    float acc = 0.f;
#pragma unroll
    for (int ky = 0; ky < 4; ++ky) {
        int ynum = y + 1 - ky;
        if (ynum & 1) continue;
        int iy = ynum >> 1;
        if (iy < 0 || iy >= HS) continue;
#pragma unroll
        for (int kx = 0; kx < 4; ++kx) {
            int xnum = x + 1 - kx;
            if (xnum & 1) continue;
            int ix = xnum >> 1;
            if (ix < 0 || ix >= WS) continue;
            acc += h2f(Gb[(size_t)(iy * WS + ix) * J2 + c * 16 + ky * 4 + kx]);
        }
    }
    float cy = (y == 0 || y == HF - 1) ? 1.f : 2.f;
    float cx = (x == 0 || x == WF - 1) ? 1.f : 2.f;
    out[idx] = acc / (cy * cx);
}

extern "C" void kernel_launch(void* const* d_in, const int* in_sizes, int n_in,
                              void* d_out, int out_size, void* d_ws, size_t ws_size,
                              hipStream_t stream) {
    const float* x       = (const float*)d_in[0];
    const float* context = (const float*)d_in[1];
    const float* mask    = (const float*)d_in[2];

    float* out = (float*)d_out;                                  // [4][96][96][96]
    float* att_region = out + (size_t)BN_ * CC * HF * WF;        // [4][2304][2304] fp32

    // workspace layout (bytes); proven ws_size >= 148,672,512 (rounds 3-7).
    //  phase A (through GEMM1): cols/xp f16-splits @0..63,700,992 ; S @63,700,992..148,635,648
    //  phase B (fuse..finish): F lives in d_out att region; Th f16 @0 (dead cols/xp) ;
    //           stats @141,557,760 (dead S tail after fuse)
    //  phase C (after finish; S dead): RF f16 @84,934,656 ; G f16 @113,246,208
    //  maskadd @148,635,648 ; ssum/invn @63,700,992 (dead before S written)
    char* wsb = (char*)d_ws;
    const size_t EK1 = (size_t)BN_ * LL * K1;      // 7,962,624
    const size_t ERF = (size_t)BN_ * J2 * LL;      // 14,155,776
    unsigned short* cols_hi = (unsigned short*)wsb;
    unsigned short* cols_lo = cols_hi + EK1;
    unsigned short* xp_hi   = cols_lo + EK1;
    unsigned short* xp_lo   = xp_hi + EK1;
    float* S = (float*)(wsb + 63700992);
    unsigned short* Th = (unsigned short*)wsb;                    // phase B
    unsigned short* RF = (unsigned short*)(wsb + 84934656);       // phase C (S dead)
    unsigned short* G  = (unsigned short*)(wsb + 113246208);
    float* pm    = (float*)(wsb + 141557760);                     // [4][8][2304]
    float* ps    = pm + (size_t)BN_ * 8 * LL;
    float* mstat = ps + (size_t)BN_ * 8 * LL;                     // [4][2304]
    float* sinv  = mstat + BN_ * LL;
    float* ssum    = (float*)(wsb + 63700992);                    // dead before S written
    float* invn    = ssum + BN_ * HS * WS;
    float* maskadd = (float*)(wsb + 148635648);

    ssum_kernel<<<(BN_ * HS * WS + 255) / 256, 256, 0, stream>>>(context, ssum);
    invn_kernel<<<(BN_ * LL + 255) / 256, 256, 0, stream>>>(ssum, invn);
    mask_kernel<<<(BN_ * LL + 255) / 256, 256, 0, stream>>>(mask, maskadd);

    im2col_split<<<(int)(EK1 / 256), 256, 0, stream>>>(x, nullptr, xp_hi, xp_lo);
    im2col_split<<<(int)(EK1 / 256), 256, 0, stream>>>(context, invn, cols_hi, cols_lo);

    // GEMM1 (3-term f16 split, single-buffer): S[l][p] = cols . xp^T (fp32)
    gemm_split<3, 0><<<(LL / 128) * (LL / 128) * BN_, 256, 0, stream>>>(
        cols_hi, cols_lo, xp_hi, xp_lo, S, LL, LL, K1, LL / 128, LL / 128);

    // fuse (both conv_eye passes) + mask + x10 -> att_region (d_out)
    fuse_kernel<<<(int)((size_t)BN_ * LL * LL / 256), 256, 0, stream>>>(S, maskadd, att_region);

    // softmax over l: coalesced column stats + in-place finish (emits f16 attT)
    colstat_kernel<<<dim3(LL / 64, 8, BN_), 256, 0, stream>>>(att_region, pm, ps);
    mergestat_kernel<<<(BN_ * LL + 255) / 256, 256, 0, stream>>>(pm, ps, mstat, sinv);
    finish_kernel<<<dim3(LL / 64, LL / 64, BN_), 256, 0, stream>>>(att_region, mstat, sinv, Th);

    // raw filters f16 (S dead now)
    rf_split<<<(int)(ERF / 256), 256, 0, stream>>>(context, RF);

    // GEMM2 (1-term f16, 2-phase dbuf): G[p][j] = att^T . RF^T  (f16 out)
    gemm_split<1, 1><<<(J2 / 128) * (LL / 128) * BN_, 256, 0, stream>>>(
        Th, nullptr, RF, nullptr, G, LL, J2, LL, J2 / 128, LL / 128);

    // col2im gather + overlap normalization -> out
    col2im_kernel<<<(BN_ * CC * HF * WF + 255) / 256, 256, 0, stream>>>(G, out);
}

// Round 9
// 455.795 us; speedup vs baseline: 1.2601x; 1.1369x over previous
//
#include <hip/hip_runtime.h>
#include <stdint.h>

// Problem constants (N,C,H,W)=(4,96,96,96), half-res 48x48
#define BN_ 4
#define CC 96
#define HF 96
#define WF 96
#define HS 48
#define WS 48
#define LL 2304      // HS*WS
#define K1 864       // CC*9  (3x3 patch feature dim)
#define J2 1536      // CC*16 (4x4 raw filter feature dim)
#define NEG10 (-1.0e10f)

typedef __attribute__((ext_vector_type(8))) _Float16 half8v;
typedef __attribute__((ext_vector_type(4))) float float4v;
typedef float float4u __attribute__((ext_vector_type(4), aligned(4)));  // unaligned-capable

__device__ __forceinline__ int Tswap(int f) { return (f % 48) * 48 + f / 48; }

__device__ __forceinline__ unsigned short f2h(float f) {
    _Float16 h = (_Float16)f;
    return __builtin_bit_cast(unsigned short, h);
}
__device__ __forceinline__ float h2f(unsigned short u) {
    return (float)__builtin_bit_cast(_Float16, u);
}

typedef const __attribute__((address_space(1))) uint32_t* gas_ptr;
typedef __attribute__((address_space(3))) uint32_t* las_ptr;
__device__ __forceinline__ void gload16(const void* g, void* l) {
    __builtin_amdgcn_global_load_lds((gas_ptr)g, (las_ptr)l, 16, 0, 0);
}

// ---- channel-sum-of-squares of strided context: ssum[n][i][j] ----
__global__ void ssum_kernel(const float* __restrict__ ctx, float* __restrict__ ssum) {
    int idx = blockIdx.x * 256 + threadIdx.x;
    if (idx >= BN_ * HS * WS) return;
    int j = idx % WS, i = (idx / WS) % HS, n = idx / (WS * HS);
    float s = 0.f;
    for (int c = 0; c < CC; ++c) {
        float v = ctx[((size_t)(n * CC + c) * HF + 2 * i) * WF + 2 * j];
        s += v * v;
    }
    ssum[idx] = s;
}

// ---- invn[n][l] = 1/max(sqrt(sum 3x3 ssum),1e-4) ----
__global__ void invn_kernel(const float* __restrict__ ssum, float* __restrict__ invn) {
    int idx = blockIdx.x * 256 + threadIdx.x;
    if (idx >= BN_ * LL) return;
    int l = idx % LL, n = idx / LL;
    int i0 = l / WS, j0 = l % WS;
    float s = 0.f;
    for (int dy = -1; dy <= 1; ++dy)
        for (int dx = -1; dx <= 1; ++dx) {
            int i = i0 + dy, j = j0 + dx;
            if (i >= 0 && i < HS && j >= 0 && j < WS)
                s += ssum[(n * HS + i) * WS + j];
        }
    invn[idx] = 1.f / fmaxf(sqrtf(s), 1e-4f);
}

// ---- maskadd[n][l] ----
__global__ void mask_kernel(const float* __restrict__ mask, float* __restrict__ maskadd) {
    int idx = blockIdx.x * 256 + threadIdx.x;
    if (idx >= BN_ * LL) return;
    int l = idx % LL, n = idx / LL;
    int i0 = l / WS, j0 = l % WS;
    float s = 0.f;
    for (int dy = -1; dy <= 1; ++dy)
        for (int dx = -1; dx <= 1; ++dx) {
            int i = i0 + dy, j = j0 + dx;
            if (i >= 0 && i < HS && j >= 0 && j < WS)
                s += mask[(size_t)n * HF * WF + (2 * i) * WF + 2 * j];
        }
    maskadd[idx] = (s > 0.f) ? NEG10 : 0.f;
}

// ---- im2col 3x3 (pad 1) of ::2 slice + f16 hi/lo split; dst [n][l][864] k-major ----
__global__ void im2col_split(const float* __restrict__ src, const float* __restrict__ scale,
                             unsigned short* __restrict__ hi, unsigned short* __restrict__ lo) {
    int idx = blockIdx.x * 256 + threadIdx.x;
    if (idx >= BN_ * LL * K1) return;
    int k = idx % K1;
    int l = (idx / K1) % LL;
    int n = idx / (K1 * LL);
    int c = k / 9, r = k % 9;
    int i = l / WS + r / 3 - 1;
    int j = l % WS + r % 3 - 1;
    float v = 0.f;
    if (i >= 0 && i < HS && j >= 0 && j < WS)
        v = src[((size_t)(n * CC + c) * HF + 2 * i) * WF + 2 * j];
    if (scale) v *= scale[n * LL + l];
    unsigned short h = f2h(v);
    hi[idx] = h;
    lo[idx] = f2h(v - h2f(h));
}

// ---- raw filter, transposed, f16: RF[n][j][l] ----
__global__ void rf_split(const float* __restrict__ ctx, unsigned short* __restrict__ hf) {
    int idx = blockIdx.x * 256 + threadIdx.x;
    if (idx >= BN_ * J2 * LL) return;
    int l = idx % LL;
    int j = (idx / LL) % J2;
    int n = idx / (LL * J2);
    int c = j >> 4, ky = (j >> 2) & 3, kx = j & 3;
    int y = 2 * (l / WS) + ky - 1;
    int x = 2 * (l % WS) + kx - 1;
    float v = 0.f;
    if (y >= 0 && y < HF && x >= 0 && x < WF)
        v = ctx[((size_t)(n * CC + c) * HF + y) * WF + x];
    hf[idx] = f2h(v);
}

// ---- f16 MFMA GEMM: C[m][n] = sum_k A[m][k]*B[n][k] ----
// TERMS=3: Ah*Bh + Ah*Bl + Al*Bh (hi/lo f16 split), single-buffer (32 KB LDS).
// TERMS=1: Ah*Bh, 2-phase double-buffered (32 KB LDS total).
// ODT: 0 = fp32 out, 1 = f16 out. Flat 1D grid + XCD chunk swizzle (grid%8==0).
template <int TERMS, int ODT>
__global__ __launch_bounds__(256, 4) void gemm_split(
    const unsigned short* __restrict__ Ah_, const unsigned short* __restrict__ Al_,
    const unsigned short* __restrict__ Bh_, const unsigned short* __restrict__ Bl_,
    void* __restrict__ Cout, int M_, int N_, int K_, int nbx, int nby)
{
    constexpr int NB = (TERMS == 3) ? 4 : 2;
    constexpr int BH = (TERMS == 3) ? 2 : 1;       // B_hi LDS buffer index
    constexpr int NBUF = (TERMS == 1) ? 2 : 1;     // dbuf only for the light GEMM
    constexpr int BUFS = NB * 128 * 32;            // shorts per dbuf
    __shared__ unsigned short lds[NBUF][NB][128][32];

    int wg = blockIdx.x;
    int wgid = (wg & 7) * (gridDim.x >> 3) + (wg >> 3);
    int bx = wgid % nbx;
    int t1 = wgid / nbx;
    int by = t1 % nby;
    int bz = t1 / nby;
    const int m0 = by * 128, n0 = bx * 128;
    const int t = threadIdx.x;

    const size_t sA = (size_t)M_ * K_, sB = (size_t)N_ * K_;
    const unsigned short* Ah = Ah_ + (size_t)bz * sA;
    const unsigned short* Bh = Bh_ + (size_t)bz * sB;

    const int rloc = t >> 2;
    const int sst = t & 3;
    const int kg = sst ^ ((rloc >> 1) & 3);
    const size_t offA0 = (size_t)(m0 + rloc) * K_ + kg * 8;
    const size_t offA1 = (size_t)(m0 + 64 + rloc) * K_ + kg * 8;
    const size_t offB0 = (size_t)(n0 + rloc) * K_ + kg * 8;
    const size_t offB1 = (size_t)(n0 + 64 + rloc) * K_ + kg * 8;
    const unsigned short* gpA0 = Ah + offA0;
    const unsigned short* gpA1 = Ah + offA1;
    const unsigned short* gpB0 = Bh + offB0;
    const unsigned short* gpB1 = Bh + offB1;
    const unsigned short* gpAl0 = nullptr;
    const unsigned short* gpAl1 = nullptr;
    const unsigned short* gpBl0 = nullptr;
    const unsigned short* gpBl1 = nullptr;
    if constexpr (TERMS == 3) {
        const unsigned short* Al = Al_ + (size_t)bz * sA;
        const unsigned short* Bl = Bl_ + (size_t)bz * sB;
        gpAl0 = Al + offA0;
        gpAl1 = Al + offA1;
        gpBl0 = Bl + offB0;
        gpBl1 = Bl + offB1;
    }
    // per-thread LDS short-offsets (within one buffer set)
    const int oA0 = (0 * 128 + rloc) * 32 + sst * 8;
    const int oA1 = (0 * 128 + 64 + rloc) * 32 + sst * 8;
    const int oAl0 = (1 * 128 + rloc) * 32 + sst * 8;
    const int oAl1 = (1 * 128 + 64 + rloc) * 32 + sst * 8;
    const int oB0 = (BH * 128 + rloc) * 32 + sst * 8;
    const int oB1 = (BH * 128 + 64 + rloc) * 32 + sst * 8;
    const int oBl0 = (3 * 128 + rloc) * 32 + sst * 8;
    const int oBl1 = (3 * 128 + 64 + rloc) * 32 + sst * 8;
    unsigned short* L = &lds[0][0][0][0];

#define STAGEB(buf) do { \
        unsigned short* Lb = L + (buf) * BUFS; \
        gload16(gpA0, Lb + oA0); gload16(gpA1, Lb + oA1); \
        gload16(gpB0, Lb + oB0); gload16(gpB1, Lb + oB1); \
        if constexpr (TERMS == 3) { \
            gload16(gpAl0, Lb + oAl0); gload16(gpAl1, Lb + oAl1); \
            gload16(gpBl0, Lb + oBl0); gload16(gpBl1, Lb + oBl1); \
        } \
        gpA0 += 32; gpA1 += 32; gpB0 += 32; gpB1 += 32; \
        if constexpr (TERMS == 3) { gpAl0 += 32; gpAl1 += 32; gpBl0 += 32; gpBl1 += 32; } \
    } while (0)

    const int lane = t & 63;
    const int w = t >> 6, wr = w >> 1, wc = w & 1;
    const int lr = lane & 15, lg = lane >> 4;

    float4v acc[4][4] = {};
    const int nt = K_ / 32;

#define COMPUTE(buf) do { \
        half8v bh[4], bl[4]; \
        _Pragma("unroll") \
        for (int j = 0; j < 4; ++j) { \
            int row = wc * 64 + j * 16 + lr; \
            int s = (lg ^ ((row >> 1) & 3)) * 8; \
            bh[j] = *(const half8v*)&lds[buf][BH][row][s]; \
            if constexpr (TERMS == 3) bl[j] = *(const half8v*)&lds[buf][3][row][s]; \
        } \
        _Pragma("unroll") \
        for (int i = 0; i < 4; ++i) { \
            int row = wr * 64 + i * 16 + lr; \
            int s = (lg ^ ((row >> 1) & 3)) * 8; \
            half8v ah = *(const half8v*)&lds[buf][0][row][s]; \
            _Pragma("unroll") \
            for (int j = 0; j < 4; ++j) { \
                acc[i][j] = __builtin_amdgcn_mfma_f32_16x16x32_f16(ah, bh[j], acc[i][j], 0, 0, 0); \
                if constexpr (TERMS == 3) { \
                    half8v al = *(const half8v*)&lds[buf][1][row][s]; \
                    acc[i][j] = __builtin_amdgcn_mfma_f32_16x16x32_f16(ah, bl[j], acc[i][j], 0, 0, 0); \
                    acc[i][j] = __builtin_amdgcn_mfma_f32_16x16x32_f16(al, bh[j], acc[i][j], 0, 0, 0); \
                } \
            } \
        } \
    } while (0)

    if constexpr (NBUF == 1) {
        // single-buffer 1-phase (proven round-6 structure)
        for (int kt = 0; kt < nt; ++kt) {
            __syncthreads();
            STAGEB(0);
            __syncthreads();
            COMPUTE(0);
        }
    } else {
        // 2-phase double-buffered (32 KB total)
        STAGEB(0);
        __syncthreads();
        int cur = 0;
        for (int kt = 0; kt < nt; ++kt) {
            if (kt + 1 < nt) STAGEB(cur ^ 1);
            COMPUTE(cur);
            __syncthreads();
            cur ^= 1;
        }
    }
#undef STAGEB
#undef COMPUTE

    if constexpr (ODT == 0) {
        float* Cb = (float*)Cout + (size_t)bz * M_ * N_;
#pragma unroll
        for (int i = 0; i < 4; ++i) {
            int mb = m0 + wr * 64 + i * 16 + lg * 4;
#pragma unroll
            for (int j = 0; j < 4; ++j) {
                int nn = n0 + wc * 64 + j * 16 + lr;
#pragma unroll
                for (int r = 0; r < 4; ++r)
                    Cb[(size_t)(mb + r) * N_ + nn] = acc[i][j][r];
            }
        }
    } else {
        unsigned short* Gb = (unsigned short*)Cout + (size_t)bz * M_ * N_;
#pragma unroll
        for (int i = 0; i < 4; ++i) {
            int mb = m0 + wr * 64 + i * 16 + lg * 4;
#pragma unroll
            for (int j = 0; j < 4; ++j) {
                int nn = n0 + wc * 64 + j * 16 + lr;
#pragma unroll
                for (int r = 0; r < 4; ++r)
                    Gb[(size_t)(mb + r) * N_ + nn] = f2h(acc[i][j][r]);
            }
        }
    }
}

// ---- fused double conv_eye + mask + x10, vectorized: one thread per 4-p quad ----
// Key identity: for 4 consecutive p in an aligned quad (pj<=44+3, never crosses a
// 48-row), Tswap(Tswap(p+e)+d2) = p2b + e in ALL wrap cases, so each tap is one
// contiguous (unaligned) float4 load with per-lane validity masks.
__global__ void fuse_kernel(const float* __restrict__ S, const float* __restrict__ maskadd,
                            float* __restrict__ Sf) {
    int wg = blockIdx.x;
    int wgid = (wg & 7) * (gridDim.x >> 3) + (wg >> 3);   // XCD chunk swizzle (grid%8==0)
    int idx = wgid * 256 + threadIdx.x;                    // BN_*LL*576 quads
    int q = idx % 576;
    int l = (idx / 576) % LL;
    int n = idx / (576 * LL);
    int p0 = q * 4;
    const float* Sb = S + (size_t)n * LL * LL;
    int Tl = Tswap(l);
    int Tp0 = Tswap(p0);
    float4v acc = {0.f, 0.f, 0.f, 0.f};
#pragma unroll
    for (int d2 = -1; d2 <= 1; ++d2) {
        int fl = Tl + d2;
        if (fl < 0 || fl >= LL) continue;          // kills all 4 lanes (l-side)
        int fp0 = Tp0 + d2;                        // in [-1, 2304]
        if (fp0 >= LL) continue;                   // lane0 biggest? no: lanes grow; all invalid
        int l2 = Tswap(fl);
        int ee = (fp0 < 0) ? 1 : 0;
        int p2b = Tswap(fp0 + 48 * ee) - ee;       // p2(e) = p2b + e (universal)
        bool v0 = (fp0 >= 0);
        bool v1 = (fp0 + 48 < LL);
        bool v2 = (fp0 + 96 < LL);
        bool v3 = (fp0 + 144 < LL);
#pragma unroll
        for (int d1 = -1; d1 <= 1; ++d1) {
            int l3 = l2 + d1;
            if (l3 < 0 || l3 >= LL) continue;
            int pc = p2b + d1;                     // in [-1, 2304]
            const float* row = &Sb[(size_t)l3 * LL];
            float4u v = *(const float4u*)&row[pc]; // masked-lane OOB stays inside ws
            if (v0 && pc >= 0 && pc < LL)          acc[0] += v[0];
            if (v1 && pc + 1 >= 0 && pc + 1 < LL)  acc[1] += v[1];
            if (v2 && pc + 2 < LL)                 acc[2] += v[2];
            if (v3 && pc + 3 < LL)                 acc[3] += v[3];
        }
    }
    float madd = maskadd[n * LL + l];
    float4v outv;
#pragma unroll
    for (int i = 0; i < 4; ++i) outv[i] = acc[i] * 10.f + madd;
    *(float4v*)&Sf[((size_t)n * LL + l) * LL + p0] = outv;
}

// ---- column-wise online softmax stats over F[l][p]: partial (m,s) per l-split ----
// grid (36 p-blocks, 8 l-splits, 4 n), block 256 = 64 p x 4 l-rows
__global__ __launch_bounds__(256) void colstat_kernel(const float* __restrict__ F,
                                                      float* __restrict__ pm,
                                                      float* __restrict__ ps) {
    __shared__ float ms[4][64], ss[4][64];
    int pb = blockIdx.x, lsp = blockIdx.y, n = blockIdx.z;
    int tx = threadIdx.x & 63;
    int ty = threadIdx.x >> 6;
    int p = pb * 64 + tx;
    const float* Fb = F + (size_t)n * LL * LL;
    float m = -3e38f, s = 0.f;
    int l_end = (lsp + 1) * 288;
    for (int l = lsp * 288 + ty; l < l_end; l += 4) {
        float v = Fb[(size_t)l * LL + p];
        float mm = fmaxf(m, v);
        s = s * __expf(m - mm) + __expf(v - mm);
        m = mm;
    }
    ms[ty][tx] = m; ss[ty][tx] = s;
    __syncthreads();
    if (ty == 0) {
#pragma unroll
        for (int q = 1; q < 4; ++q) {
            float m2 = ms[q][tx], s2 = ss[q][tx];
            float mm = fmaxf(m, m2);
            s = s * __expf(m - mm) + s2 * __expf(m2 - mm);
            m = mm;
        }
        pm[((size_t)n * 8 + lsp) * LL + p] = m;
        ps[((size_t)n * 8 + lsp) * LL + p] = s;
    }
}

// ---- merge 8 partials -> mstat[p], sinv[p] ----
__global__ void mergestat_kernel(const float* __restrict__ pm, const float* __restrict__ ps,
                                 float* __restrict__ mstat, float* __restrict__ sinv) {
    int idx = blockIdx.x * 256 + threadIdx.x;
    if (idx >= BN_ * LL) return;
    int n = idx / LL, p = idx % LL;
    float m = -3e38f, s = 0.f;
#pragma unroll
    for (int q = 0; q < 8; ++q) {
        float m2 = pm[((size_t)n * 8 + q) * LL + p];
        float s2 = ps[((size_t)n * 8 + q) * LL + p];
        float mm = fmaxf(m, m2);
        s = s * __expf(m - mm) + s2 * __expf(m2 - mm);
        m = mm;
    }
    mstat[idx] = m;
    sinv[idx] = 1.f / s;
}

// ---- finish 64x64: att = exp(F-m)*sinv in place (float4); emit f16 attT (32B) ----
// block 256 = 16 p-quads x 16 rows; grid (LL/64, LL/64, BN_)
__global__ __launch_bounds__(256) void finish_kernel(float* __restrict__ F,
                                                     const float* __restrict__ mstat,
                                                     const float* __restrict__ sinv,
                                                     unsigned short* __restrict__ Th) {
    __shared__ float tile[64][65];
    int n = blockIdx.z;
    int l0 = blockIdx.y * 64, p0 = blockIdx.x * 64;
    float* Fb = F + (size_t)n * LL * LL;
    int tx = threadIdx.x & 15, ty = threadIdx.x >> 4;
    float4v m4 = *(const float4v*)&mstat[n * LL + p0 + tx * 4];
    float4v s4 = *(const float4v*)&sinv[n * LL + p0 + tx * 4];
#pragma unroll
    for (int q = 0; q < 4; ++q) {
        int lr = q * 16 + ty;
        float4v v = *(const float4v*)&Fb[(size_t)(l0 + lr) * LL + p0 + tx * 4];
        float4v e;
#pragma unroll
        for (int i = 0; i < 4; ++i) e[i] = __expf(v[i] - m4[i]) * s4[i];
        *(float4v*)&Fb[(size_t)(l0 + lr) * LL + p0 + tx * 4] = e;
#pragma unroll
        for (int i = 0; i < 4; ++i) tile[lr][tx * 4 + i] = e[i];
    }
    __syncthreads();
    int pr = threadIdx.x >> 2, lq = threadIdx.x & 3;
    uint32_t u[8];
#pragma unroll
    for (int i = 0; i < 8; ++i) {
        unsigned short h0 = f2h(tile[lq * 16 + 2 * i][pr]);
        unsigned short h1 = f2h(tile[lq * 16 + 2 * i + 1][pr]);
        u[i] = (uint32_t)h0 | ((uint32_t)h1 << 16);
    }
    unsigned short* dst = &Th[((size_t)n * LL + p0 + pr) * LL + l0 + lq * 16];
    ((uint32_t*)dst)[0] = u[0]; ((uint32_t*)dst)[1] = u[1];
    ((uint32_t*)dst)[2] = u[2]; ((uint32_t*)dst)[3] = u[3];
    ((uint32_t*)dst)[4] = u[4]; ((uint32_t*)dst)[5] = u[5];
    ((uint32_t*)dst)[6] = u[6]; ((uint32_t*)dst)[7] = u[7];
}

// ---- col2im gather from f16 G[p][j] + overlap division ----
__global__ void col2im_kernel(const unsigned short* __restrict__ G, float* __restrict__ out) {
    int idx = blockIdx.x * 256 + threadIdx.x;
    if (idx >= BN_ * CC * HF * WF) return;
    int x = idx % WF;
    int y = (idx / WF) % HF;
    int c = (idx / (WF * HF)) % CC;
    int n = idx / (WF * HF * CC);
    const unsigned short* Gb = G + (size_t)n * LL * J2;
    float acc = 0.f;
#pragma unroll
    for (int ky = 0; ky < 4; ++ky) {
        int ynum = y + 1 - ky;
        if (ynum & 1) continue;
        int iy = ynum >> 1;
        if (iy < 0 || iy >= HS) continue;
#pragma unroll
        for (int kx = 0; kx < 4; ++kx) {
            int xnum = x + 1 - kx;
            if (xnum & 1) continue;
            int ix = xnum >> 1;
            if (ix < 0 || ix >= WS) continue;
            acc += h2f(Gb[(size_t)(iy * WS + ix) * J2 + c * 16 + ky * 4 + kx]);
        }
    }
    float cy = (y == 0 || y == HF - 1) ? 1.f : 2.f;
    float cx = (x == 0 || x == WF - 1) ? 1.f : 2.f;
    out[idx] = acc / (cy * cx);
}

extern "C" void kernel_launch(void* const* d_in, const int* in_sizes, int n_in,
                              void* d_out, int out_size, void* d_ws, size_t ws_size,
                              hipStream_t stream) {
    const float* x       = (const float*)d_in[0];
    const float* context = (const float*)d_in[1];
    const float* mask    = (const float*)d_in[2];

    float* out = (float*)d_out;                                  // [4][96][96][96]
    float* att_region = out + (size_t)BN_ * CC * HF * WF;        // [4][2304][2304] fp32

    // workspace layout (bytes); proven ws_size >= 148,672,512 (rounds 3-8).
    //  phase A (through GEMM1): cols/xp f16-splits @0..63,700,992 ; S @63,700,992..148,635,648
    //  phase B (fuse..finish): F lives in d_out att region; Th f16 @0 (dead cols/xp) ;
    //           stats @141,557,760 (dead S tail after fuse)
    //  phase C (after finish; S dead): RF f16 @84,934,656 ; G f16 @113,246,208
    //  maskadd @148,635,648 ; ssum/invn @63,700,992 (dead before S written)
    char* wsb = (char*)d_ws;
    const size_t EK1 = (size_t)BN_ * LL * K1;      // 7,962,624
    const size_t ERF = (size_t)BN_ * J2 * LL;      // 14,155,776
    unsigned short* cols_hi = (unsigned short*)wsb;
    unsigned short* cols_lo = cols_hi + EK1;
    unsigned short* xp_hi   = cols_lo + EK1;
    unsigned short* xp_lo   = xp_hi + EK1;
    float* S = (float*)(wsb + 63700992);
    unsigned short* Th = (unsigned short*)wsb;                    // phase B
    unsigned short* RF = (unsigned short*)(wsb + 84934656);       // phase C (S dead)
    unsigned short* G  = (unsigned short*)(wsb + 113246208);
    float* pm    = (float*)(wsb + 141557760);                     // [4][8][2304]
    float* ps    = pm + (size_t)BN_ * 8 * LL;
    float* mstat = ps + (size_t)BN_ * 8 * LL;                     // [4][2304]
    float* sinv  = mstat + BN_ * LL;
    float* ssum    = (float*)(wsb + 63700992);                    // dead before S written
    float* invn    = ssum + BN_ * HS * WS;
    float* maskadd = (float*)(wsb + 148635648);

    ssum_kernel<<<(BN_ * HS * WS + 255) / 256, 256, 0, stream>>>(context, ssum);
    invn_kernel<<<(BN_ * LL + 255) / 256, 256, 0, stream>>>(ssum, invn);
    mask_kernel<<<(BN_ * LL + 255) / 256, 256, 0, stream>>>(mask, maskadd);

    im2col_split<<<(int)(EK1 / 256), 256, 0, stream>>>(x, nullptr, xp_hi, xp_lo);
    im2col_split<<<(int)(EK1 / 256), 256, 0, stream>>>(context, invn, cols_hi, cols_lo);

    // GEMM1 (3-term f16 split, single-buffer): S[l][p] = cols . xp^T (fp32)
    gemm_split<3, 0><<<(LL / 128) * (LL / 128) * BN_, 256, 0, stream>>>(
        cols_hi, cols_lo, xp_hi, xp_lo, S, LL, LL, K1, LL / 128, LL / 128);

    // fuse (both conv_eye passes) + mask + x10 -> att_region (d_out), 4-p vectorized
    fuse_kernel<<<(int)((size_t)BN_ * LL * 576 / 256), 256, 0, stream>>>(S, maskadd, att_region);

    // softmax over l: coalesced column stats + in-place finish (emits f16 attT)
    colstat_kernel<<<dim3(LL / 64, 8, BN_), 256, 0, stream>>>(att_region, pm, ps);
    mergestat_kernel<<<(BN_ * LL + 255) / 256, 256, 0, stream>>>(pm, ps, mstat, sinv);
    finish_kernel<<<dim3(LL / 64, LL / 64, BN_), 256, 0, stream>>>(att_region, mstat, sinv, Th);

    // raw filters f16 (S dead now)
    rf_split<<<(int)(ERF / 256), 256, 0, stream>>>(context, RF);

    // GEMM2 (1-term f16, 2-phase dbuf): G[p][j] = att^T . RF^T  (f16 out)
    gemm_split<1, 1><<<(J2 / 128) * (LL / 128) * BN_, 256, 0, stream>>>(
        Th, nullptr, RF, nullptr, G, LL, J2, LL, J2 / 128, LL / 128);

    // col2im gather + overlap normalization -> out
    col2im_kernel<<<(BN_ * CC * HF * WF + 255) / 256, 256, 0, stream>>>(G, out);
}

// Round 10
// 376.435 us; speedup vs baseline: 1.5257x; 1.2108x over previous
//
#include <hip/hip_runtime.h>
#include <stdint.h>

// Problem constants (N,C,H,W)=(4,96,96,96), half-res 48x48
#define BN_ 4
#define CC 96
#define HF 96
#define WF 96
#define HS 48
#define WS 48
#define LL 2304      // HS*WS
#define J2 1536      // CC*16 (4x4 raw filter feature dim)
#define NEG10 (-1.0e10f)

typedef __attribute__((ext_vector_type(8))) _Float16 half8v;
typedef __attribute__((ext_vector_type(4))) float float4v;
typedef float float4u __attribute__((ext_vector_type(4), aligned(4)));  // unaligned-capable

__device__ __forceinline__ int Tswap(int f) { return (f % 48) * 48 + f / 48; }

__device__ __forceinline__ unsigned short f2h(float f) {
    _Float16 h = (_Float16)f;
    return __builtin_bit_cast(unsigned short, h);
}
__device__ __forceinline__ float h2f(unsigned short u) {
    return (float)__builtin_bit_cast(_Float16, u);
}

typedef const __attribute__((address_space(1))) uint32_t* gas_ptr;
typedef __attribute__((address_space(3))) uint32_t* las_ptr;
__device__ __forceinline__ void gload16(const void* g, void* l) {
    __builtin_amdgcn_global_load_lds((gas_ptr)g, (las_ptr)l, 16, 0, 0);
}

// ---- channel-sum-of-squares of strided context: ssum[n][i][j] ----
__global__ void ssum_kernel(const float* __restrict__ ctx, float* __restrict__ ssum) {
    int idx = blockIdx.x * 256 + threadIdx.x;
    if (idx >= BN_ * HS * WS) return;
    int j = idx % WS, i = (idx / WS) % HS, n = idx / (WS * HS);
    float s = 0.f;
    for (int c = 0; c < CC; ++c) {
        float v = ctx[((size_t)(n * CC + c) * HF + 2 * i) * WF + 2 * j];
        s += v * v;
    }
    ssum[idx] = s;
}

// ---- invn[n][l] = 1/max(sqrt(sum 3x3 ssum),1e-4) ----
__global__ void invn_kernel(const float* __restrict__ ssum, float* __restrict__ invn) {
    int idx = blockIdx.x * 256 + threadIdx.x;
    if (idx >= BN_ * LL) return;
    int l = idx % LL, n = idx / LL;
    int i0 = l / WS, j0 = l % WS;
    float s = 0.f;
    for (int dy = -1; dy <= 1; ++dy)
        for (int dx = -1; dx <= 1; ++dx) {
            int i = i0 + dy, j = j0 + dx;
            if (i >= 0 && i < HS && j >= 0 && j < WS)
                s += ssum[(n * HS + i) * WS + j];
        }
    invn[idx] = 1.f / fmaxf(sqrtf(s), 1e-4f);
}

// ---- maskadd[n][l] ----
__global__ void mask_kernel(const float* __restrict__ mask, float* __restrict__ maskadd) {
    int idx = blockIdx.x * 256 + threadIdx.x;
    if (idx >= BN_ * LL) return;
    int l = idx % LL, n = idx / LL;
    int i0 = l / WS, j0 = l % WS;
    float s = 0.f;
    for (int dy = -1; dy <= 1; ++dy)
        for (int dx = -1; dx <= 1; ++dx) {
            int i = i0 + dy, j = j0 + dx;
            if (i >= 0 && i < HS && j >= 0 && j < WS)
                s += mask[(size_t)n * HF * WF + (2 * i) * WF + 2 * j];
        }
    maskadd[idx] = (s > 0.f) ? NEG10 : 0.f;
}

// ---- strided slice + f16 hi/lo split: dst[n][u][c] (c-major, K=96) ----
__global__ void slice_split(const float* __restrict__ src,
                            unsigned short* __restrict__ hi, unsigned short* __restrict__ lo) {
    int idx = blockIdx.x * 256 + threadIdx.x;
    if (idx >= BN_ * LL * CC) return;
    int c = idx % CC;
    int u = (idx / CC) % LL;
    int n = idx / (CC * LL);
    int i = u / WS, j = u % WS;
    float v = src[((size_t)(n * CC + c) * HF + 2 * i) * WF + 2 * j];
    unsigned short h = f2h(v);
    hi[idx] = h;
    lo[idx] = f2h(v - h2f(h));
}

// ---- raw filter, transposed, f16: RF[n][j][l] ----
__global__ void rf_split(const float* __restrict__ ctx, unsigned short* __restrict__ hf) {
    int idx = blockIdx.x * 256 + threadIdx.x;
    if (idx >= BN_ * J2 * LL) return;
    int l = idx % LL;
    int j = (idx / LL) % J2;
    int n = idx / (LL * J2);
    int c = j >> 4, ky = (j >> 2) & 3, kx = j & 3;
    int y = 2 * (l / WS) + ky - 1;
    int x = 2 * (l % WS) + kx - 1;
    float v = 0.f;
    if (y >= 0 && y < HF && x >= 0 && x < WF)
        v = ctx[((size_t)(n * CC + c) * HF + y) * WF + x];
    hf[idx] = f2h(v);
}

// ---- f16 MFMA GEMM: C[m][n] = sum_k A[m][k]*B[n][k] ----
// TERMS=3: Ah*Bh + Ah*Bl + Al*Bh (hi/lo f16 split), single-buffer (32 KB LDS).
// TERMS=1: Ah*Bh, 2-phase double-buffered (32 KB LDS total).
// ODT: 0 = fp32 out, 1 = f16 out. Flat 1D grid + XCD chunk swizzle (grid%8==0).
template <int TERMS, int ODT>
__global__ __launch_bounds__(256, 4) void gemm_split(
    const unsigned short* __restrict__ Ah_, const unsigned short* __restrict__ Al_,
    const unsigned short* __restrict__ Bh_, const unsigned short* __restrict__ Bl_,
    void* __restrict__ Cout, int M_, int N_, int K_, int nbx, int nby)
{
    constexpr int NB = (TERMS == 3) ? 4 : 2;
    constexpr int BH = (TERMS == 3) ? 2 : 1;       // B_hi LDS buffer index
    constexpr int NBUF = (TERMS == 1) ? 2 : 1;     // dbuf only for the light GEMM
    constexpr int BUFS = NB * 128 * 32;            // shorts per dbuf
    __shared__ unsigned short lds[NBUF][NB][128][32];

    int wg = blockIdx.x;
    int wgid = (wg & 7) * (gridDim.x >> 3) + (wg >> 3);
    int bx = wgid % nbx;
    int t1 = wgid / nbx;
    int by = t1 % nby;
    int bz = t1 / nby;
    const int m0 = by * 128, n0 = bx * 128;
    const int t = threadIdx.x;

    const size_t sA = (size_t)M_ * K_, sB = (size_t)N_ * K_;
    const unsigned short* Ah = Ah_ + (size_t)bz * sA;
    const unsigned short* Bh = Bh_ + (size_t)bz * sB;

    const int rloc = t >> 2;
    const int sst = t & 3;
    const int kg = sst ^ ((rloc >> 1) & 3);
    const size_t offA0 = (size_t)(m0 + rloc) * K_ + kg * 8;
    const size_t offA1 = (size_t)(m0 + 64 + rloc) * K_ + kg * 8;
    const size_t offB0 = (size_t)(n0 + rloc) * K_ + kg * 8;
    const size_t offB1 = (size_t)(n0 + 64 + rloc) * K_ + kg * 8;
    const unsigned short* gpA0 = Ah + offA0;
    const unsigned short* gpA1 = Ah + offA1;
    const unsigned short* gpB0 = Bh + offB0;
    const unsigned short* gpB1 = Bh + offB1;
    const unsigned short* gpAl0 = nullptr;
    const unsigned short* gpAl1 = nullptr;
    const unsigned short* gpBl0 = nullptr;
    const unsigned short* gpBl1 = nullptr;
    if constexpr (TERMS == 3) {
        const unsigned short* Al = Al_ + (size_t)bz * sA;
        const unsigned short* Bl = Bl_ + (size_t)bz * sB;
        gpAl0 = Al + offA0;
        gpAl1 = Al + offA1;
        gpBl0 = Bl + offB0;
        gpBl1 = Bl + offB1;
    }
    // per-thread LDS short-offsets (within one buffer set)
    const int oA0 = (0 * 128 + rloc) * 32 + sst * 8;
    const int oA1 = (0 * 128 + 64 + rloc) * 32 + sst * 8;
    const int oAl0 = (1 * 128 + rloc) * 32 + sst * 8;
    const int oAl1 = (1 * 128 + 64 + rloc) * 32 + sst * 8;
    const int oB0 = (BH * 128 + rloc) * 32 + sst * 8;
    const int oB1 = (BH * 128 + 64 + rloc) * 32 + sst * 8;
    const int oBl0 = (3 * 128 + rloc) * 32 + sst * 8;
    const int oBl1 = (3 * 128 + 64 + rloc) * 32 + sst * 8;
    unsigned short* L = &lds[0][0][0][0];

#define STAGEB(buf) do { \
        unsigned short* Lb = L + (buf) * BUFS; \
        gload16(gpA0, Lb + oA0); gload16(gpA1, Lb + oA1); \
        gload16(gpB0, Lb + oB0); gload16(gpB1, Lb + oB1); \
        if constexpr (TERMS == 3) { \
            gload16(gpAl0, Lb + oAl0); gload16(gpAl1, Lb + oAl1); \
            gload16(gpBl0, Lb + oBl0); gload16(gpBl1, Lb + oBl1); \
        } \
        gpA0 += 32; gpA1 += 32; gpB0 += 32; gpB1 += 32; \
        if constexpr (TERMS == 3) { gpAl0 += 32; gpAl1 += 32; gpBl0 += 32; gpBl1 += 32; } \
    } while (0)

    const int lane = t & 63;
    const int w = t >> 6, wr = w >> 1, wc = w & 1;
    const int lr = lane & 15, lg = lane >> 4;

    float4v acc[4][4] = {};
    const int nt = K_ / 32;

#define COMPUTE(buf) do { \
        half8v bh[4], bl[4]; \
        _Pragma("unroll") \
        for (int j = 0; j < 4; ++j) { \
            int row = wc * 64 + j * 16 + lr; \
            int s = (lg ^ ((row >> 1) & 3)) * 8; \
            bh[j] = *(const half8v*)&lds[buf][BH][row][s]; \
            if constexpr (TERMS == 3) bl[j] = *(const half8v*)&lds[buf][3][row][s]; \
        } \
        _Pragma("unroll") \
        for (int i = 0; i < 4; ++i) { \
            int row = wr * 64 + i * 16 + lr; \
            int s = (lg ^ ((row >> 1) & 3)) * 8; \
            half8v ah = *(const half8v*)&lds[buf][0][row][s]; \
            _Pragma("unroll") \
            for (int j = 0; j < 4; ++j) { \
                acc[i][j] = __builtin_amdgcn_mfma_f32_16x16x32_f16(ah, bh[j], acc[i][j], 0, 0, 0); \
                if constexpr (TERMS == 3) { \
                    half8v al = *(const half8v*)&lds[buf][1][row][s]; \
                    acc[i][j] = __builtin_amdgcn_mfma_f32_16x16x32_f16(ah, bl[j], acc[i][j], 0, 0, 0); \
                    acc[i][j] = __builtin_amdgcn_mfma_f32_16x16x32_f16(al, bh[j], acc[i][j], 0, 0, 0); \
                } \
            } \
        } \
    } while (0)

    if constexpr (NBUF == 1) {
        for (int kt = 0; kt < nt; ++kt) {
            __syncthreads();
            STAGEB(0);
            __syncthreads();
            COMPUTE(0);
        }
    } else {
        STAGEB(0);
        __syncthreads();
        int cur = 0;
        for (int kt = 0; kt < nt; ++kt) {
            if (kt + 1 < nt) STAGEB(cur ^ 1);
            COMPUTE(cur);
            __syncthreads();
            cur ^= 1;
        }
    }
#undef STAGEB
#undef COMPUTE

    if constexpr (ODT == 0) {
        float* Cb = (float*)Cout + (size_t)bz * M_ * N_;
#pragma unroll
        for (int i = 0; i < 4; ++i) {
            int mb = m0 + wr * 64 + i * 16 + lg * 4;
#pragma unroll
            for (int j = 0; j < 4; ++j) {
                int nn = n0 + wc * 64 + j * 16 + lr;
#pragma unroll
                for (int r = 0; r < 4; ++r)
                    Cb[(size_t)(mb + r) * N_ + nn] = acc[i][j][r];
            }
        }
    } else {
        unsigned short* Gb = (unsigned short*)Cout + (size_t)bz * M_ * N_;
#pragma unroll
        for (int i = 0; i < 4; ++i) {
            int mb = m0 + wr * 64 + i * 16 + lg * 4;
#pragma unroll
            for (int j = 0; j < 4; ++j) {
                int nn = n0 + wc * 64 + j * 16 + lr;
#pragma unroll
                for (int r = 0; r < 4; ++r)
                    Gb[(size_t)(mb + r) * N_ + nn] = f2h(acc[i][j][r]);
            }
        }
    }
}

// ---- gatherS: S[l][p] = invn[l] * sum_{dy,dx} E[l+k, p+k], k=48*dy+dx ----
// (patch-GEMM factorization; taps gated by strict 2D validity = zero-padding)
// One thread per 4-p quad, 9 unaligned float4 taps, per-lane masks.
__global__ void gatherS(const float* __restrict__ E, const float* __restrict__ invn,
                        float* __restrict__ S) {
    int wg = blockIdx.x;
    int wgid = (wg & 7) * (gridDim.x >> 3) + (wg >> 3);   // XCD chunk swizzle
    int idx = wgid * 256 + threadIdx.x;                    // BN_*LL*576 quads
    int q = idx % 576;
    int l = (idx / 576) % LL;
    int n = idx / (576 * LL);
    int p0 = q * 4;
    int li = l / WS, lj = l % WS;
    int pi = p0 / WS, pj = p0 % WS;                        // quad never crosses a row (48%4==0)
    const float* Eb = E + (size_t)n * LL * LL;
    float4v acc = {0.f, 0.f, 0.f, 0.f};
#pragma unroll
    for (int dy = -1; dy <= 1; ++dy) {
        if (li + dy < 0 || li + dy >= HS) continue;
        if (pi + dy < 0 || pi + dy >= HS) continue;
#pragma unroll
        for (int dx = -1; dx <= 1; ++dx) {
            if (lj + dx < 0 || lj + dx >= WS) continue;
            int k = dy * WS + dx;
            const float* row = &Eb[(size_t)(l + k) * LL];
            float4u v = *(const float4u*)&row[p0 + k];     // masked-lane OOB stays in ws
            bool v0 = (pj + dx >= 0);                      // lane0 fails only dx=-1,pj=0
            bool v3 = (pj + 3 + dx < WS);                  // lane3 fails only dx=+1,pj=44
            if (v0) acc[0] += v[0];
            acc[1] += v[1];
            acc[2] += v[2];
            if (v3) acc[3] += v[3];
        }
    }
    float iv = invn[n * LL + l];
    float4v outv;
#pragma unroll
    for (int i = 0; i < 4; ++i) outv[i] = acc[i] * iv;
    *(float4v*)&S[((size_t)n * LL + l) * LL + p0] = outv;
}

// ---- fused double conv_eye + mask + x10, vectorized: one thread per 4-p quad ----
__global__ void fuse_kernel(const float* __restrict__ S, const float* __restrict__ maskadd,
                            float* __restrict__ Sf) {
    int wg = blockIdx.x;
    int wgid = (wg & 7) * (gridDim.x >> 3) + (wg >> 3);   // XCD chunk swizzle (grid%8==0)
    int idx = wgid * 256 + threadIdx.x;                    // BN_*LL*576 quads
    int q = idx % 576;
    int l = (idx / 576) % LL;
    int n = idx / (576 * LL);
    int p0 = q * 4;
    const float* Sb = S + (size_t)n * LL * LL;
    int Tl = Tswap(l);
    int Tp0 = Tswap(p0);
    float4v acc = {0.f, 0.f, 0.f, 0.f};
#pragma unroll
    for (int d2 = -1; d2 <= 1; ++d2) {
        int fl = Tl + d2;
        if (fl < 0 || fl >= LL) continue;
        int fp0 = Tp0 + d2;
        if (fp0 >= LL) continue;
        int l2 = Tswap(fl);
        int ee = (fp0 < 0) ? 1 : 0;
        int p2b = Tswap(fp0 + 48 * ee) - ee;       // p2(e) = p2b + e (universal)
        bool v0 = (fp0 >= 0);
        bool v1 = (fp0 + 48 < LL);
        bool v2 = (fp0 + 96 < LL);
        bool v3 = (fp0 + 144 < LL);
#pragma unroll
        for (int d1 = -1; d1 <= 1; ++d1) {
            int l3 = l2 + d1;
            if (l3 < 0 || l3 >= LL) continue;
            int pc = p2b + d1;
            const float* row = &Sb[(size_t)l3 * LL];
            float4u v = *(const float4u*)&row[pc];
            if (v0 && pc >= 0 && pc < LL)          acc[0] += v[0];
            if (v1 && pc + 1 >= 0 && pc + 1 < LL)  acc[1] += v[1];
            if (v2 && pc + 2 < LL)                 acc[2] += v[2];
            if (v3 && pc + 3 < LL)                 acc[3] += v[3];
        }
    }
    float madd = maskadd[n * LL + l];
    float4v outv;
#pragma unroll
    for (int i = 0; i < 4; ++i) outv[i] = acc[i] * 10.f + madd;
    *(float4v*)&Sf[((size_t)n * LL + l) * LL + p0] = outv;
}

// ---- column-wise online softmax stats over F[l][p]: partial (m,s) per l-split ----
__global__ __launch_bounds__(256) void colstat_kernel(const float* __restrict__ F,
                                                      float* __restrict__ pm,
                                                      float* __restrict__ ps) {
    __shared__ float ms[4][64], ss[4][64];
    int pb = blockIdx.x, lsp = blockIdx.y, n = blockIdx.z;
    int tx = threadIdx.x & 63;
    int ty = threadIdx.x >> 6;
    int p = pb * 64 + tx;
    const float* Fb = F + (size_t)n * LL * LL;
    float m = -3e38f, s = 0.f;
    int l_end = (lsp + 1) * 288;
    for (int l = lsp * 288 + ty; l < l_end; l += 4) {
        float v = Fb[(size_t)l * LL + p];
        float mm = fmaxf(m, v);
        s = s * __expf(m - mm) + __expf(v - mm);
        m = mm;
    }
    ms[ty][tx] = m; ss[ty][tx] = s;
    __syncthreads();
    if (ty == 0) {
#pragma unroll
        for (int q = 1; q < 4; ++q) {
            float m2 = ms[q][tx], s2 = ss[q][tx];
            float mm = fmaxf(m, m2);
            s = s * __expf(m - mm) + s2 * __expf(m2 - mm);
            m = mm;
        }
        pm[((size_t)n * 8 + lsp) * LL + p] = m;
        ps[((size_t)n * 8 + lsp) * LL + p] = s;
    }
}

// ---- merge 8 partials -> mstat[p], sinv[p] ----
__global__ void mergestat_kernel(const float* __restrict__ pm, const float* __restrict__ ps,
                                 float* __restrict__ mstat, float* __restrict__ sinv) {
    int idx = blockIdx.x * 256 + threadIdx.x;
    if (idx >= BN_ * LL) return;
    int n = idx / LL, p = idx % LL;
    float m = -3e38f, s = 0.f;
#pragma unroll
    for (int q = 0; q < 8; ++q) {
        float m2 = pm[((size_t)n * 8 + q) * LL + p];
        float s2 = ps[((size_t)n * 8 + q) * LL + p];
        float mm = fmaxf(m, m2);
        s = s * __expf(m - mm) + s2 * __expf(m2 - mm);
        m = mm;
    }
    mstat[idx] = m;
    sinv[idx] = 1.f / s;
}

// ---- finish 64x64: att = exp(F-m)*sinv -> att_out (float4); emit f16 attT (32B) ----
__global__ __launch_bounds__(256) void finish_kernel(const float* __restrict__ F,
                                                     const float* __restrict__ mstat,
                                                     const float* __restrict__ sinv,
                                                     float* __restrict__ att,
                                                     unsigned short* __restrict__ Th) {
    __shared__ float tile[64][65];
    int n = blockIdx.z;
    int l0 = blockIdx.y * 64, p0 = blockIdx.x * 64;
    const float* Fb = F + (size_t)n * LL * LL;
    float* Ab = att + (size_t)n * LL * LL;
    int tx = threadIdx.x & 15, ty = threadIdx.x >> 4;
    float4v m4 = *(const float4v*)&mstat[n * LL + p0 + tx * 4];
    float4v s4 = *(const float4v*)&sinv[n * LL + p0 + tx * 4];
#pragma unroll
    for (int q = 0; q < 4; ++q) {
        int lr = q * 16 + ty;
        float4v v = *(const float4v*)&Fb[(size_t)(l0 + lr) * LL + p0 + tx * 4];
        float4v e;
#pragma unroll
        for (int i = 0; i < 4; ++i) e[i] = __expf(v[i] - m4[i]) * s4[i];
        *(float4v*)&Ab[(size_t)(l0 + lr) * LL + p0 + tx * 4] = e;
#pragma unroll
        for (int i = 0; i < 4; ++i) tile[lr][tx * 4 + i] = e[i];
    }
    __syncthreads();
    int pr = threadIdx.x >> 2, lq = threadIdx.x & 3;
    uint32_t u[8];
#pragma unroll
    for (int i = 0; i < 8; ++i) {
        unsigned short h0 = f2h(tile[lq * 16 + 2 * i][pr]);
        unsigned short h1 = f2h(tile[lq * 16 + 2 * i + 1][pr]);
        u[i] = (uint32_t)h0 | ((uint32_t)h1 << 16);
    }
    unsigned short* dst = &Th[((size_t)n * LL + p0 + pr) * LL + l0 + lq * 16];
    ((uint32_t*)dst)[0] = u[0]; ((uint32_t*)dst)[1] = u[1];
    ((uint32_t*)dst)[2] = u[2]; ((uint32_t*)dst)[3] = u[3];
    ((uint32_t*)dst)[4] = u[4]; ((uint32_t*)dst)[5] = u[5];
    ((uint32_t*)dst)[6] = u[6]; ((uint32_t*)dst)[7] = u[7];
}

// ---- col2im gather from f16 G[p][j] + overlap division ----
__global__ void col2im_kernel(const unsigned short* __restrict__ G, float* __restrict__ out) {
    int idx = blockIdx.x * 256 + threadIdx.x;
    if (idx >= BN_ * CC * HF * WF) return;
    int x = idx % WF;
    int y = (idx / WF) % HF;
    int c = (idx / (WF * HF)) % CC;
    int n = idx / (WF * HF * CC);
    const unsigned short* Gb = G + (size_t)n * LL * J2;
    float acc = 0.f;
#pragma unroll
    for (int ky = 0; ky < 4; ++ky) {
        int ynum = y + 1 - ky;
        if (ynum & 1) continue;
        int iy = ynum >> 1;
        if (iy < 0 || iy >= HS) continue;
#pragma unroll
        for (int kx = 0; kx < 4; ++kx) {
            int xnum = x + 1 - kx;
            if (xnum & 1) continue;
            int ix = xnum >> 1;
            if (ix < 0 || ix >= WS) continue;
            acc += h2f(Gb[(size_t)(iy * WS + ix) * J2 + c * 16 + ky * 4 + kx]);
        }
    }
    float cy = (y == 0 || y == HF - 1) ? 1.f : 2.f;
    float cx = (x == 0 || x == WF - 1) ? 1.f : 2.f;
    out[idx] = acc / (cy * cx);
}

extern "C" void kernel_launch(void* const* d_in, const int* in_sizes, int n_in,
                              void* d_out, int out_size, void* d_ws, size_t ws_size,
                              hipStream_t stream) {
    const float* x       = (const float*)d_in[0];
    const float* context = (const float*)d_in[1];
    const float* mask    = (const float*)d_in[2];

    float* out = (float*)d_out;                                  // [4][96][96][96]
    float* att_region = out + (size_t)BN_ * CC * HF * WF;        // [4][2304][2304] fp32

    // workspace (bytes); proven ws_size >= 148,672,512.
    //  Th @0 (42.47M, written by finish) ; stats/invn/ssum @42.47M.. ;
    //  cs/xs f16 splits @44.04M (7.08M, dead after GEMM0) ;
    //  big region @63,700,992 (84.93M): E (GEMM0 out) -> F (fuse out) -> RF+G (phase C) ;
    //  maskadd @148,635,648 (tail).
    char* wsb = (char*)d_ws;
    const size_t ESL = (size_t)BN_ * LL * CC;      // 884,736 elements
    const size_t ERF = (size_t)BN_ * J2 * LL;      // 14,155,776
    unsigned short* Th = (unsigned short*)wsb;                    // [4][2304][2304] f16
    float* pm    = (float*)(wsb + 42467328);                      // [4][8][2304]
    float* ps    = (float*)(wsb + 42762240);
    float* mstat = (float*)(wsb + 43057152);                      // [4][2304]
    float* sinv  = (float*)(wsb + 43094016);
    float* invn  = (float*)(wsb + 43130880);
    float* ssum  = (float*)(wsb + 43167744);
    unsigned short* cs_hi = (unsigned short*)(wsb + 44040192);
    unsigned short* cs_lo = cs_hi + ESL;
    unsigned short* xs_hi = cs_lo + ESL;
    unsigned short* xs_lo = xs_hi + ESL;                          // ends ~51.1M
    float* E = (float*)(wsb + 63700992);                          // [4][2304][2304] fp32
    float* F = (float*)(wsb + 63700992);                          // overlays E after gatherS
    unsigned short* RF = (unsigned short*)(wsb + 63700992);       // overlays F after finish
    unsigned short* G  = (unsigned short*)(wsb + 92012544);
    float* maskadd = (float*)(wsb + 148635648);
    float* S = att_region;                                        // S lives in d_out att region

    ssum_kernel<<<(BN_ * HS * WS + 255) / 256, 256, 0, stream>>>(context, ssum);
    invn_kernel<<<(BN_ * LL + 255) / 256, 256, 0, stream>>>(ssum, invn);
    mask_kernel<<<(BN_ * LL + 255) / 256, 256, 0, stream>>>(mask, maskadd);

    // strided-slice channel splits (K=96 operands)
    slice_split<<<(int)(ESL / 256), 256, 0, stream>>>(context, cs_hi, cs_lo);
    slice_split<<<(int)(ESL / 256), 256, 0, stream>>>(x, xs_hi, xs_lo);

    // GEMM0 (3-term f16 split, K=96): E[u][v] = cs . xs^T (fp32)
    gemm_split<3, 0><<<(LL / 128) * (LL / 128) * BN_, 256, 0, stream>>>(
        cs_hi, cs_lo, xs_hi, xs_lo, E, LL, LL, CC, LL / 128, LL / 128);

    // patch-sum factorization: S[l][p] = invn[l] * 9-tap diagonal gather of E
    gatherS<<<(int)((size_t)BN_ * LL * 576 / 256), 256, 0, stream>>>(E, invn, S);

    // fuse (both conv_eye passes) + mask + x10: S (d_out) -> F (ws, over dead E)
    fuse_kernel<<<(int)((size_t)BN_ * LL * 576 / 256), 256, 0, stream>>>(S, maskadd, F);

    // softmax over l: coalesced column stats; finish writes att (d_out) + f16 attT
    colstat_kernel<<<dim3(LL / 64, 8, BN_), 256, 0, stream>>>(F, pm, ps);
    mergestat_kernel<<<(BN_ * LL + 255) / 256, 256, 0, stream>>>(pm, ps, mstat, sinv);
    finish_kernel<<<dim3(LL / 64, LL / 64, BN_), 256, 0, stream>>>(F, mstat, sinv, att_region, Th);

    // raw filters f16 (F dead now; RF overlays it)
    rf_split<<<(int)(ERF / 256), 256, 0, stream>>>(context, RF);

    // GEMM2 (1-term f16, 2-phase dbuf): G[p][j] = att^T . RF^T  (f16 out)
    gemm_split<1, 1><<<(J2 / 128) * (LL / 128) * BN_, 256, 0, stream>>>(
        Th, nullptr, RF, nullptr, G, LL, J2, LL, J2 / 128, LL / 128);

    // col2im gather + overlap normalization -> out
    col2im_kernel<<<(BN_ * CC * HF * WF + 255) / 256, 256, 0, stream>>>(G, out);
}

// Round 11
// 349.929 us; speedup vs baseline: 1.6413x; 1.0757x over previous
//
#include <hip/hip_runtime.h>
#include <stdint.h>

// Problem constants (N,C,H,W)=(4,96,96,96), half-res 48x48
#define BN_ 4
#define CC 96
#define HF 96
#define WF 96
#define HS 48
#define WS 48
#define LL 2304      // HS*WS
#define J2 1536      // CC*16 (4x4 raw filter feature dim)
#define NEG10 (-1.0e10f)

typedef __attribute__((ext_vector_type(8))) _Float16 half8v;
typedef __attribute__((ext_vector_type(4))) float float4v;
typedef float float4u __attribute__((ext_vector_type(4), aligned(4)));  // unaligned-capable

__device__ __forceinline__ int Tswap(int f) { return (f % 48) * 48 + f / 48; }

__device__ __forceinline__ unsigned short f2h(float f) {
    _Float16 h = (_Float16)f;
    return __builtin_bit_cast(unsigned short, h);
}
__device__ __forceinline__ float h2f(unsigned short u) {
    return (float)__builtin_bit_cast(_Float16, u);
}

typedef const __attribute__((address_space(1))) uint32_t* gas_ptr;
typedef __attribute__((address_space(3))) uint32_t* las_ptr;
__device__ __forceinline__ void gload16(const void* g, void* l) {
    __builtin_amdgcn_global_load_lds((gas_ptr)g, (las_ptr)l, 16, 0, 0);
}

// ---- channel-sum-of-squares of strided context: ssum[n][i][j] ----
__global__ void ssum_kernel(const float* __restrict__ ctx, float* __restrict__ ssum) {
    int idx = blockIdx.x * 256 + threadIdx.x;
    if (idx >= BN_ * HS * WS) return;
    int j = idx % WS, i = (idx / WS) % HS, n = idx / (WS * HS);
    float s = 0.f;
    for (int c = 0; c < CC; ++c) {
        float v = ctx[((size_t)(n * CC + c) * HF + 2 * i) * WF + 2 * j];
        s += v * v;
    }
    ssum[idx] = s;
}

// ---- invn[n][l] = 1/max(sqrt(sum 3x3 ssum),1e-4) ----
__global__ void invn_kernel(const float* __restrict__ ssum, float* __restrict__ invn) {
    int idx = blockIdx.x * 256 + threadIdx.x;
    if (idx >= BN_ * LL) return;
    int l = idx % LL, n = idx / LL;
    int i0 = l / WS, j0 = l % WS;
    float s = 0.f;
    for (int dy = -1; dy <= 1; ++dy)
        for (int dx = -1; dx <= 1; ++dx) {
            int i = i0 + dy, j = j0 + dx;
            if (i >= 0 && i < HS && j >= 0 && j < WS)
                s += ssum[(n * HS + i) * WS + j];
        }
    invn[idx] = 1.f / fmaxf(sqrtf(s), 1e-4f);
}

// ---- maskadd[n][l] ----
__global__ void mask_kernel(const float* __restrict__ mask, float* __restrict__ maskadd) {
    int idx = blockIdx.x * 256 + threadIdx.x;
    if (idx >= BN_ * LL) return;
    int l = idx % LL, n = idx / LL;
    int i0 = l / WS, j0 = l % WS;
    float s = 0.f;
    for (int dy = -1; dy <= 1; ++dy)
        for (int dx = -1; dx <= 1; ++dx) {
            int i = i0 + dy, j = j0 + dx;
            if (i >= 0 && i < HS && j >= 0 && j < WS)
                s += mask[(size_t)n * HF * WF + (2 * i) * WF + 2 * j];
        }
    maskadd[idx] = (s > 0.f) ? NEG10 : 0.f;
}

// ---- strided slice + f16 hi/lo split for BOTH tensors: dst[n][u][c] (c-major) ----
__global__ void slice_split2(const float* __restrict__ ctx, const float* __restrict__ x,
                             unsigned short* __restrict__ cs_hi, unsigned short* __restrict__ cs_lo,
                             unsigned short* __restrict__ xs_hi, unsigned short* __restrict__ xs_lo) {
    int idx = blockIdx.x * 256 + threadIdx.x;
    if (idx >= BN_ * LL * CC) return;
    const float* src = blockIdx.y ? x : ctx;
    unsigned short* hi = blockIdx.y ? xs_hi : cs_hi;
    unsigned short* lo = blockIdx.y ? xs_lo : cs_lo;
    int c = idx % CC;
    int u = (idx / CC) % LL;
    int n = idx / (CC * LL);
    int i = u / WS, j = u % WS;
    float v = src[((size_t)(n * CC + c) * HF + 2 * i) * WF + 2 * j];
    unsigned short h = f2h(v);
    hi[idx] = h;
    lo[idx] = f2h(v - h2f(h));
}

// ---- raw filter, transposed, f16: RF[n][j][l] ----
__global__ void rf_split(const float* __restrict__ ctx, unsigned short* __restrict__ hf) {
    int idx = blockIdx.x * 256 + threadIdx.x;
    if (idx >= BN_ * J2 * LL) return;
    int l = idx % LL;
    int j = (idx / LL) % J2;
    int n = idx / (LL * J2);
    int c = j >> 4, ky = (j >> 2) & 3, kx = j & 3;
    int y = 2 * (l / WS) + ky - 1;
    int x = 2 * (l % WS) + kx - 1;
    float v = 0.f;
    if (y >= 0 && y < HF && x >= 0 && x < WF)
        v = ctx[((size_t)(n * CC + c) * HF + y) * WF + x];
    hf[idx] = f2h(v);
}

// ---- f16 MFMA GEMM (TERMS=3 split, BK=32, single-buffer): C fp32 ----
__global__ __launch_bounds__(256, 4) void gemm_split3(
    const unsigned short* __restrict__ Ah_, const unsigned short* __restrict__ Al_,
    const unsigned short* __restrict__ Bh_, const unsigned short* __restrict__ Bl_,
    float* __restrict__ Cout, int M_, int N_, int K_, int nbx, int nby)
{
    __shared__ unsigned short lds[4][128][32];

    int wg = blockIdx.x;
    int wgid = (wg & 7) * (gridDim.x >> 3) + (wg >> 3);
    int bx = wgid % nbx;
    int t1 = wgid / nbx;
    int by = t1 % nby;
    int bz = t1 / nby;
    const int m0 = by * 128, n0 = bx * 128;
    const int t = threadIdx.x;

    const size_t sA = (size_t)M_ * K_, sB = (size_t)N_ * K_;
    const unsigned short* Ah = Ah_ + (size_t)bz * sA;
    const unsigned short* Al = Al_ + (size_t)bz * sA;
    const unsigned short* Bh = Bh_ + (size_t)bz * sB;
    const unsigned short* Bl = Bl_ + (size_t)bz * sB;

    const int rloc = t >> 2;
    const int sst = t & 3;
    const int kg = sst ^ ((rloc >> 1) & 3);
    const size_t offA0 = (size_t)(m0 + rloc) * K_ + kg * 8;
    const size_t offA1 = (size_t)(m0 + 64 + rloc) * K_ + kg * 8;
    const size_t offB0 = (size_t)(n0 + rloc) * K_ + kg * 8;
    const size_t offB1 = (size_t)(n0 + 64 + rloc) * K_ + kg * 8;
    const unsigned short* gp0 = Ah + offA0;
    const unsigned short* gp1 = Ah + offA1;
    const unsigned short* gp2 = Al + offA0;
    const unsigned short* gp3 = Al + offA1;
    const unsigned short* gp4 = Bh + offB0;
    const unsigned short* gp5 = Bh + offB1;
    const unsigned short* gp6 = Bl + offB0;
    const unsigned short* gp7 = Bl + offB1;
    unsigned short* lp0 = &lds[0][rloc][sst * 8];
    unsigned short* lp1 = &lds[0][64 + rloc][sst * 8];
    unsigned short* lp2 = &lds[1][rloc][sst * 8];
    unsigned short* lp3 = &lds[1][64 + rloc][sst * 8];
    unsigned short* lp4 = &lds[2][rloc][sst * 8];
    unsigned short* lp5 = &lds[2][64 + rloc][sst * 8];
    unsigned short* lp6 = &lds[3][rloc][sst * 8];
    unsigned short* lp7 = &lds[3][64 + rloc][sst * 8];

    const int lane = t & 63;
    const int w = t >> 6, wr = w >> 1, wc = w & 1;
    const int lr = lane & 15, lg = lane >> 4;

    float4v acc[4][4] = {};
    const int nt = K_ / 32;

    for (int kt = 0; kt < nt; ++kt) {
        __syncthreads();
        gload16(gp0, lp0); gload16(gp1, lp1);
        gload16(gp2, lp2); gload16(gp3, lp3);
        gload16(gp4, lp4); gload16(gp5, lp5);
        gload16(gp6, lp6); gload16(gp7, lp7);
        gp0 += 32; gp1 += 32; gp2 += 32; gp3 += 32;
        gp4 += 32; gp5 += 32; gp6 += 32; gp7 += 32;
        __syncthreads();

        half8v bh[4], bl[4];
#pragma unroll
        for (int j = 0; j < 4; ++j) {
            int row = wc * 64 + j * 16 + lr;
            int s = (lg ^ ((row >> 1) & 3)) * 8;
            bh[j] = *(const half8v*)&lds[2][row][s];
            bl[j] = *(const half8v*)&lds[3][row][s];
        }
#pragma unroll
        for (int i = 0; i < 4; ++i) {
            int row = wr * 64 + i * 16 + lr;
            int s = (lg ^ ((row >> 1) & 3)) * 8;
            half8v ah = *(const half8v*)&lds[0][row][s];
            half8v al = *(const half8v*)&lds[1][row][s];
#pragma unroll
            for (int j = 0; j < 4; ++j) {
                acc[i][j] = __builtin_amdgcn_mfma_f32_16x16x32_f16(ah, bh[j], acc[i][j], 0, 0, 0);
                acc[i][j] = __builtin_amdgcn_mfma_f32_16x16x32_f16(ah, bl[j], acc[i][j], 0, 0, 0);
                acc[i][j] = __builtin_amdgcn_mfma_f32_16x16x32_f16(al, bh[j], acc[i][j], 0, 0, 0);
            }
        }
    }

    float* Cb = Cout + (size_t)bz * M_ * N_;
#pragma unroll
    for (int i = 0; i < 4; ++i) {
        int mb = m0 + wr * 64 + i * 16 + lg * 4;
#pragma unroll
        for (int j = 0; j < 4; ++j) {
            int nn = n0 + wc * 64 + j * 16 + lr;
#pragma unroll
            for (int r = 0; r < 4; ++r)
                Cb[(size_t)(mb + r) * N_ + nn] = acc[i][j][r];
        }
    }
}

// ---- f16 MFMA GEMM (1-term, BK=64, single-buffer 1-phase): C f16 ----
// 32 MFMA per compute phase, 36 iters at K=2304. LDS 32 KB. 8-slot XOR swizzle.
__global__ __launch_bounds__(256, 4) void gemm_k64(
    const unsigned short* __restrict__ Ah_, const unsigned short* __restrict__ Bh_,
    unsigned short* __restrict__ Cout, int M_, int N_, int K_, int nbx, int nby)
{
    __shared__ unsigned short lds[2][128][64];

    int wg = blockIdx.x;
    int wgid = (wg & 7) * (gridDim.x >> 3) + (wg >> 3);
    int bx = wgid % nbx;
    int t1 = wgid / nbx;
    int by = t1 % nby;
    int bz = t1 / nby;
    const int m0 = by * 128, n0 = bx * 128;
    const int t = threadIdx.x;

    const unsigned short* Ah = Ah_ + (size_t)bz * M_ * K_;
    const unsigned short* Bh = Bh_ + (size_t)bz * N_ * K_;

    // staging: 1024 16B-slots per array, 4 per thread; LDS dest linear in t (wave-uniform+lane*16)
    const unsigned short* gpA[4];
    const unsigned short* gpB[4];
    int lo[4];
#pragma unroll
    for (int rep = 0; rep < 4; ++rep) {
        int slot = t + rep * 256;
        int row = slot >> 3, sc = slot & 7;
        int kg = sc ^ (row & 7);                   // pre-swizzled global source
        gpA[rep] = Ah + (size_t)(m0 + row) * K_ + kg * 8;
        gpB[rep] = Bh + (size_t)(n0 + row) * K_ + kg * 8;
        lo[rep] = row * 64 + sc * 8;               // linear LDS dest (shorts)
    }

    const int lane = t & 63;
    const int w = t >> 6, wr = w >> 1, wc = w & 1;
    const int lr = lane & 15, lg = lane >> 4;

    float4v acc[4][4] = {};
    const int nt = K_ / 64;
    unsigned short* LA = &lds[0][0][0];
    unsigned short* LB = &lds[1][0][0];

    for (int kt = 0; kt < nt; ++kt) {
        __syncthreads();
#pragma unroll
        for (int rep = 0; rep < 4; ++rep) {
            gload16(gpA[rep], LA + lo[rep]);
            gload16(gpB[rep], LB + lo[rep]);
            gpA[rep] += 64; gpB[rep] += 64;
        }
        __syncthreads();
#pragma unroll
        for (int kk = 0; kk < 2; ++kk) {
            half8v bh[4];
#pragma unroll
            for (int j = 0; j < 4; ++j) {
                int row = wc * 64 + j * 16 + lr;
                int sc = (kk * 4 + lg) ^ (row & 7);    // same involution on read side
                bh[j] = *(const half8v*)&lds[1][row][sc * 8];
            }
#pragma unroll
            for (int i = 0; i < 4; ++i) {
                int row = wr * 64 + i * 16 + lr;
                int sc = (kk * 4 + lg) ^ (row & 7);
                half8v ah = *(const half8v*)&lds[0][row][sc * 8];
#pragma unroll
                for (int j = 0; j < 4; ++j)
                    acc[i][j] = __builtin_amdgcn_mfma_f32_16x16x32_f16(ah, bh[j], acc[i][j], 0, 0, 0);
            }
        }
    }

    unsigned short* Gb = Cout + (size_t)bz * M_ * N_;
#pragma unroll
    for (int i = 0; i < 4; ++i) {
        int mb = m0 + wr * 64 + i * 16 + lg * 4;
#pragma unroll
        for (int j = 0; j < 4; ++j) {
            int nn = n0 + wc * 64 + j * 16 + lr;
#pragma unroll
            for (int r = 0; r < 4; ++r)
                Gb[(size_t)(mb + r) * N_ + nn] = f2h(acc[i][j][r]);
        }
    }
}

// ---- gatherS: S[l][p] = invn[l] * sum_{dy,dx} E[l+k, p+k], k=48*dy+dx ----
__global__ void gatherS(const float* __restrict__ E, const float* __restrict__ invn,
                        float* __restrict__ S) {
    int wg = blockIdx.x;
    int wgid = (wg & 7) * (gridDim.x >> 3) + (wg >> 3);   // XCD chunk swizzle
    int idx = wgid * 256 + threadIdx.x;                    // BN_*LL*576 quads
    int q = idx % 576;
    int l = (idx / 576) % LL;
    int n = idx / (576 * LL);
    int p0 = q * 4;
    int li = l / WS, lj = l % WS;
    int pi = p0 / WS, pj = p0 % WS;
    const float* Eb = E + (size_t)n * LL * LL;
    float4v acc = {0.f, 0.f, 0.f, 0.f};
#pragma unroll
    for (int dy = -1; dy <= 1; ++dy) {
        if (li + dy < 0 || li + dy >= HS) continue;
        if (pi + dy < 0 || pi + dy >= HS) continue;
#pragma unroll
        for (int dx = -1; dx <= 1; ++dx) {
            if (lj + dx < 0 || lj + dx >= WS) continue;
            int k = dy * WS + dx;
            const float* row = &Eb[(size_t)(l + k) * LL];
            float4u v = *(const float4u*)&row[p0 + k];
            bool v0 = (pj + dx >= 0);
            bool v3 = (pj + 3 + dx < WS);
            if (v0) acc[0] += v[0];
            acc[1] += v[1];
            acc[2] += v[2];
            if (v3) acc[3] += v[3];
        }
    }
    float iv = invn[n * LL + l];
    float4v outv;
#pragma unroll
    for (int i = 0; i < 4; ++i) outv[i] = acc[i] * iv;
    *(float4v*)&S[((size_t)n * LL + l) * LL + p0] = outv;
}

// ---- fused double conv_eye + mask + x10, vectorized: one thread per 4-p quad ----
__global__ void fuse_kernel(const float* __restrict__ S, const float* __restrict__ maskadd,
                            float* __restrict__ Sf) {
    int wg = blockIdx.x;
    int wgid = (wg & 7) * (gridDim.x >> 3) + (wg >> 3);
    int idx = wgid * 256 + threadIdx.x;
    int q = idx % 576;
    int l = (idx / 576) % LL;
    int n = idx / (576 * LL);
    int p0 = q * 4;
    const float* Sb = S + (size_t)n * LL * LL;
    int Tl = Tswap(l);
    int Tp0 = Tswap(p0);
    float4v acc = {0.f, 0.f, 0.f, 0.f};
#pragma unroll
    for (int d2 = -1; d2 <= 1; ++d2) {
        int fl = Tl + d2;
        if (fl < 0 || fl >= LL) continue;
        int fp0 = Tp0 + d2;
        if (fp0 >= LL) continue;
        int l2 = Tswap(fl);
        int ee = (fp0 < 0) ? 1 : 0;
        int p2b = Tswap(fp0 + 48 * ee) - ee;
        bool v0 = (fp0 >= 0);
        bool v1 = (fp0 + 48 < LL);
        bool v2 = (fp0 + 96 < LL);
        bool v3 = (fp0 + 144 < LL);
#pragma unroll
        for (int d1 = -1; d1 <= 1; ++d1) {
            int l3 = l2 + d1;
            if (l3 < 0 || l3 >= LL) continue;
            int pc = p2b + d1;
            const float* row = &Sb[(size_t)l3 * LL];
            float4u v = *(const float4u*)&row[pc];
            if (v0 && pc >= 0 && pc < LL)          acc[0] += v[0];
            if (v1 && pc + 1 >= 0 && pc + 1 < LL)  acc[1] += v[1];
            if (v2 && pc + 2 < LL)                 acc[2] += v[2];
            if (v3 && pc + 3 < LL)                 acc[3] += v[3];
        }
    }
    float madd = maskadd[n * LL + l];
    float4v outv;
#pragma unroll
    for (int i = 0; i < 4; ++i) outv[i] = acc[i] * 10.f + madd;
    *(float4v*)&Sf[((size_t)n * LL + l) * LL + p0] = outv;
}

// ---- column-wise online softmax stats over F[l][p]: partial (m,s) per l-split ----
__global__ __launch_bounds__(256) void colstat_kernel(const float* __restrict__ F,
                                                      float* __restrict__ pm,
                                                      float* __restrict__ ps) {
    __shared__ float ms[4][64], ss[4][64];
    int pb = blockIdx.x, lsp = blockIdx.y, n = blockIdx.z;
    int tx = threadIdx.x & 63;
    int ty = threadIdx.x >> 6;
    int p = pb * 64 + tx;
    const float* Fb = F + (size_t)n * LL * LL;
    float m = -3e38f, s = 0.f;
    int l_end = (lsp + 1) * 288;
    for (int l = lsp * 288 + ty; l < l_end; l += 4) {
        float v = Fb[(size_t)l * LL + p];
        float mm = fmaxf(m, v);
        s = s * __expf(m - mm) + __expf(v - mm);
        m = mm;
    }
    ms[ty][tx] = m; ss[ty][tx] = s;
    __syncthreads();
    if (ty == 0) {
#pragma unroll
        for (int q = 1; q < 4; ++q) {
            float m2 = ms[q][tx], s2 = ss[q][tx];
            float mm = fmaxf(m, m2);
            s = s * __expf(m - mm) + s2 * __expf(m2 - mm);
            m = mm;
        }
        pm[((size_t)n * 8 + lsp) * LL + p] = m;
        ps[((size_t)n * 8 + lsp) * LL + p] = s;
    }
}

// ---- merge 8 partials -> mstat[p], sinv[p] ----
__global__ void mergestat_kernel(const float* __restrict__ pm, const float* __restrict__ ps,
                                 float* __restrict__ mstat, float* __restrict__ sinv) {
    int idx = blockIdx.x * 256 + threadIdx.x;
    if (idx >= BN_ * LL) return;
    int n = idx / LL, p = idx % LL;
    float m = -3e38f, s = 0.f;
#pragma unroll
    for (int q = 0; q < 8; ++q) {
        float m2 = pm[((size_t)n * 8 + q) * LL + p];
        float s2 = ps[((size_t)n * 8 + q) * LL + p];
        float mm = fmaxf(m, m2);
        s = s * __expf(m - mm) + s2 * __expf(m2 - mm);
        m = mm;
    }
    mstat[idx] = m;
    sinv[idx] = 1.f / s;
}

// ---- finish 64x64: att = exp(F-m)*sinv -> att_out (float4); emit f16 attT (32B) ----
__global__ __launch_bounds__(256) void finish_kernel(const float* __restrict__ F,
                                                     const float* __restrict__ mstat,
                                                     const float* __restrict__ sinv,
                                                     float* __restrict__ att,
                                                     unsigned short* __restrict__ Th) {
    __shared__ float tile[64][65];
    int n = blockIdx.z;
    int l0 = blockIdx.y * 64, p0 = blockIdx.x * 64;
    const float* Fb = F + (size_t)n * LL * LL;
    float* Ab = att + (size_t)n * LL * LL;
    int tx = threadIdx.x & 15, ty = threadIdx.x >> 4;
    float4v m4 = *(const float4v*)&mstat[n * LL + p0 + tx * 4];
    float4v s4 = *(const float4v*)&sinv[n * LL + p0 + tx * 4];
#pragma unroll
    for (int q = 0; q < 4; ++q) {
        int lr = q * 16 + ty;
        float4v v = *(const float4v*)&Fb[(size_t)(l0 + lr) * LL + p0 + tx * 4];
        float4v e;
#pragma unroll
        for (int i = 0; i < 4; ++i) e[i] = __expf(v[i] - m4[i]) * s4[i];
        *(float4v*)&Ab[(size_t)(l0 + lr) * LL + p0 + tx * 4] = e;
#pragma unroll
        for (int i = 0; i < 4; ++i) tile[lr][tx * 4 + i] = e[i];
    }
    __syncthreads();
    int pr = threadIdx.x >> 2, lq = threadIdx.x & 3;
    uint32_t u[8];
#pragma unroll
    for (int i = 0; i < 8; ++i) {
        unsigned short h0 = f2h(tile[lq * 16 + 2 * i][pr]);
        unsigned short h1 = f2h(tile[lq * 16 + 2 * i + 1][pr]);
        u[i] = (uint32_t)h0 | ((uint32_t)h1 << 16);
    }
    unsigned short* dst = &Th[((size_t)n * LL + p0 + pr) * LL + l0 + lq * 16];
    ((uint32_t*)dst)[0] = u[0]; ((uint32_t*)dst)[1] = u[1];
    ((uint32_t*)dst)[2] = u[2]; ((uint32_t*)dst)[3] = u[3];
    ((uint32_t*)dst)[4] = u[4]; ((uint32_t*)dst)[5] = u[5];
    ((uint32_t*)dst)[6] = u[6]; ((uint32_t*)dst)[7] = u[7];
}

// ---- col2im gather from f16 G[p][j] + overlap division ----
__global__ void col2im_kernel(const unsigned short* __restrict__ G, float* __restrict__ out) {
    int idx = blockIdx.x * 256 + threadIdx.x;
    if (idx >= BN_ * CC * HF * WF) return;
    int x = idx % WF;
    int y = (idx / WF) % HF;
    int c = (idx / (WF * HF)) % CC;
    int n = idx / (WF * HF * CC);
    const unsigned short* Gb = G + (size_t)n * LL * J2;
    float acc = 0.f;
#pragma unroll
    for (int ky = 0; ky < 4; ++ky) {
        int ynum = y + 1 - ky;
        if (ynum & 1) continue;
        int iy = ynum >> 1;
        if (iy < 0 || iy >= HS) continue;
#pragma unroll
        for (int kx = 0; kx < 4; ++kx) {
            int xnum = x + 1 - kx;
            if (xnum & 1) continue;
            int ix = xnum >> 1;
            if (ix < 0 || ix >= WS) continue;
            acc += h2f(Gb[(size_t)(iy * WS + ix) * J2 + c * 16 + ky * 4 + kx]);
        }
    }
    float cy = (y == 0 || y == HF - 1) ? 1.f : 2.f;
    float cx = (x == 0 || x == WF - 1) ? 1.f : 2.f;
    out[idx] = acc / (cy * cx);
}

extern "C" void kernel_launch(void* const* d_in, const int* in_sizes, int n_in,
                              void* d_out, int out_size, void* d_ws, size_t ws_size,
                              hipStream_t stream) {
    const float* x       = (const float*)d_in[0];
    const float* context = (const float*)d_in[1];
    const float* mask    = (const float*)d_in[2];

    float* out = (float*)d_out;                                  // [4][96][96][96]
    float* att_region = out + (size_t)BN_ * CC * HF * WF;        // [4][2304][2304] fp32

    // workspace (bytes); proven ws_size >= 148,672,512.
    //  Th @0 (42.47M) ; stats/invn/ssum @42.47M.. ; cs/xs @44.04M (dead after GEMM0) ;
    //  big region @63,700,992: E -> F -> RF+G ; maskadd @148,635,648.
    char* wsb = (char*)d_ws;
    const size_t ESL = (size_t)BN_ * LL * CC;      // 884,736 elements
    const size_t ERF = (size_t)BN_ * J2 * LL;      // 14,155,776
    unsigned short* Th = (unsigned short*)wsb;                    // [4][2304][2304] f16
    float* pm    = (float*)(wsb + 42467328);                      // [4][8][2304]
    float* ps    = (float*)(wsb + 42762240);
    float* mstat = (float*)(wsb + 43057152);                      // [4][2304]
    float* sinv  = (float*)(wsb + 43094016);
    float* invn  = (float*)(wsb + 43130880);
    float* ssum  = (float*)(wsb + 43167744);
    unsigned short* cs_hi = (unsigned short*)(wsb + 44040192);
    unsigned short* cs_lo = cs_hi + ESL;
    unsigned short* xs_hi = cs_lo + ESL;
    unsigned short* xs_lo = xs_hi + ESL;
    float* E = (float*)(wsb + 63700992);                          // [4][2304][2304] fp32
    float* F = (float*)(wsb + 63700992);                          // overlays E after gatherS
    unsigned short* RF = (unsigned short*)(wsb + 63700992);       // overlays F after finish
    unsigned short* G  = (unsigned short*)(wsb + 92012544);
    float* maskadd = (float*)(wsb + 148635648);
    float* S = att_region;                                        // S lives in d_out att region

    ssum_kernel<<<(BN_ * HS * WS + 255) / 256, 256, 0, stream>>>(context, ssum);
    invn_kernel<<<(BN_ * LL + 255) / 256, 256, 0, stream>>>(ssum, invn);
    mask_kernel<<<(BN_ * LL + 255) / 256, 256, 0, stream>>>(mask, maskadd);

    // strided-slice channel splits (K=96 operands), both tensors in one launch
    slice_split2<<<dim3((int)(ESL / 256), 2), 256, 0, stream>>>(
        context, x, cs_hi, cs_lo, xs_hi, xs_lo);

    // GEMM0 (3-term f16 split, K=96): E[u][v] = cs . xs^T (fp32)
    gemm_split3<<<(LL / 128) * (LL / 128) * BN_, 256, 0, stream>>>(
        cs_hi, cs_lo, xs_hi, xs_lo, E, LL, LL, CC, LL / 128, LL / 128);

    // patch-sum factorization: S[l][p] = invn[l] * 9-tap diagonal gather of E
    gatherS<<<(int)((size_t)BN_ * LL * 576 / 256), 256, 0, stream>>>(E, invn, S);

    // fuse (both conv_eye passes) + mask + x10: S (d_out) -> F (ws, over dead E)
    fuse_kernel<<<(int)((size_t)BN_ * LL * 576 / 256), 256, 0, stream>>>(S, maskadd, F);

    // softmax over l: coalesced column stats; finish writes att (d_out) + f16 attT
    colstat_kernel<<<dim3(LL / 64, 8, BN_), 256, 0, stream>>>(F, pm, ps);
    mergestat_kernel<<<(BN_ * LL + 255) / 256, 256, 0, stream>>>(pm, ps, mstat, sinv);
    finish_kernel<<<dim3(LL / 64, LL / 64, BN_), 256, 0, stream>>>(F, mstat, sinv, att_region, Th);

    // raw filters f16 (F dead now; RF overlays it)
    rf_split<<<(int)(ERF / 256), 256, 0, stream>>>(context, RF);

    // GEMM2 (1-term f16, BK=64): G[p][j] = att^T . RF^T  (f16 out)
    gemm_k64<<<(J2 / 128) * (LL / 128) * BN_, 256, 0, stream>>>(
        Th, RF, G, LL, J2, LL, J2 / 128, LL / 128);

    // col2im gather + overlap normalization -> out
    col2im_kernel<<<(BN_ * CC * HF * WF + 255) / 256, 256, 0, stream>>>(G, out);
}